// Round 2
// baseline (7896.126 us; speedup 1.0000x reference)
//
#include <hip/hip_runtime.h>
#include <math.h>

#define B_ 2
#define T_ 2048
#define D_ 1024
#define H_ 16
#define HD_ 64
// qkv row stride = 3*D_ = 3072

// ---------------------------------------------------------------------------
// RoPE tables: cos/sin [T_][32], computed in double then rounded to f32.
// angle = (float)t * (float)(10000^{-2i/64}) to mimic the reference's f32 product.
__global__ __launch_bounds__(256) void rope_tables(float* __restrict__ cosT,
                                                   float* __restrict__ sinT) {
    int idx = blockIdx.x * 256 + threadIdx.x;   // t*32 + i, 65536 total
    int t = idx >> 5, i = idx & 31;
    double invf_d = exp(-((double)(2 * i) / 64.0) * 9.210340371976184); // ln(10000)
    float invf = (float)invf_d;
    float ang = (float)t * invf;
    cosT[idx] = (float)cos((double)ang);
    sinT[idx] = (float)sin((double)ang);
}

// ---------------------------------------------------------------------------
// C[M,N] = A[M,K] @ B[N,K]^T (+ bias).  64x64 tile, 256 threads, 4x4 micro.
template <int BIAS>
__global__ __launch_bounds__(256) void gemm_bt(const float* __restrict__ A,
                                               const float* __restrict__ Bm,
                                               const float* __restrict__ bias,
                                               float* __restrict__ C,
                                               int M, int N, int K) {
    __shared__ float As[16][64];
    __shared__ float Bs[16][64];
    const int tid = threadIdx.x;
    const int tx = tid & 15, ty = tid >> 4;
    const int m0 = blockIdx.y * 64, n0 = blockIdx.x * 64;
    const int lr = tid >> 2;            // 0..63 tile row
    const int lk = (tid & 3) << 2;      // 0,4,8,12
    float acc[4][4] = {};
    for (int k0 = 0; k0 < K; k0 += 16) {
        float4 a4 = *reinterpret_cast<const float4*>(&A[(size_t)(m0 + lr) * K + k0 + lk]);
        float4 b4 = *reinterpret_cast<const float4*>(&Bm[(size_t)(n0 + lr) * K + k0 + lk]);
        As[lk + 0][lr] = a4.x; As[lk + 1][lr] = a4.y;
        As[lk + 2][lr] = a4.z; As[lk + 3][lr] = a4.w;
        Bs[lk + 0][lr] = b4.x; Bs[lk + 1][lr] = b4.y;
        Bs[lk + 2][lr] = b4.z; Bs[lk + 3][lr] = b4.w;
        __syncthreads();
#pragma unroll
        for (int kk = 0; kk < 16; ++kk) {
            float4 av = *reinterpret_cast<const float4*>(&As[kk][ty << 2]);
            float4 bv = *reinterpret_cast<const float4*>(&Bs[kk][tx << 2]);
            float a_[4] = {av.x, av.y, av.z, av.w};
            float b_[4] = {bv.x, bv.y, bv.z, bv.w};
#pragma unroll
            for (int i = 0; i < 4; ++i)
#pragma unroll
                for (int j = 0; j < 4; ++j) acc[i][j] += a_[i] * b_[j];
        }
        __syncthreads();
    }
#pragma unroll
    for (int i = 0; i < 4; ++i) {
        int row = m0 + (ty << 2) + i;
        int col = n0 + (tx << 2);
        float4 o;
        o.x = acc[i][0]; o.y = acc[i][1]; o.z = acc[i][2]; o.w = acc[i][3];
        if (BIAS) {
            o.x += bias[col + 0]; o.y += bias[col + 1];
            o.z += bias[col + 2]; o.w += bias[col + 3];
        }
        *reinterpret_cast<float4*>(&C[(size_t)row * N + col]) = o;
    }
}

// ---------------------------------------------------------------------------
// In-place RoPE on q and k columns of qkv [B*T, 3072].
// out[j<32]  = v[j]*c[j]    - v[2j+1]*s[j]
// out[j>=32] = v[j]*c[j-32] + v[2(j-32)]*s[j-32]
__global__ __launch_bounds__(256) void rope_apply(float* __restrict__ qkv,
                                                  const float* __restrict__ cosT,
                                                  const float* __restrict__ sinT) {
    int idx = blockIdx.x * 256 + threadIdx.x;   // 131072 = B*T*2*H
    int h = idx & 15;
    int sel = (idx >> 4) & 1;                   // 0=q, 1=k
    int t = (idx >> 5) & 2047;
    int b = idx >> 16;
    float* p = qkv + ((size_t)(b * T_ + t)) * 3072 + sel * 1024 + h * 64;
    float v[64];
#pragma unroll
    for (int d = 0; d < 64; d += 4) {
        float4 f = *reinterpret_cast<const float4*>(p + d);
        v[d] = f.x; v[d + 1] = f.y; v[d + 2] = f.z; v[d + 3] = f.w;
    }
    const float* c = cosT + t * 32;
    const float* s = sinT + t * 32;
    float o[64];
#pragma unroll
    for (int i = 0; i < 32; ++i) {
        float ci = c[i], si = s[i];
        o[i]      = v[i]      * ci - v[2 * i + 1] * si;
        o[i + 32] = v[i + 32] * ci + v[2 * i]     * si;
    }
#pragma unroll
    for (int d = 0; d < 64; d += 4) {
        float4 f;
        f.x = o[d]; f.y = o[d + 1]; f.z = o[d + 2]; f.w = o[d + 3];
        *reinterpret_cast<float4*>(p + d) = f;
    }
}

// ---------------------------------------------------------------------------
// Attention: one block per (b, h, 4 q-rows). Scores for 4 rows kept in LDS.
__global__ __launch_bounds__(256) void attn_kernel(const float* __restrict__ qkv,
                                                   float* __restrict__ ctx) {
    __shared__ float qs[4][64];
    __shared__ float sl[4][T_];
    __shared__ float red[4][4][64];
    __shared__ float inv_s[4];
    const int tid = threadIdx.x;
    const int bh = blockIdx.y;
    const int b = bh >> 4, h = bh & 15;
    const int t0 = blockIdx.x << 2;
    const size_t base = (size_t)b * T_ * 3072;

    {   // load 4 q rows, pre-scaled by 1/sqrt(64)
        int r = tid >> 6, d = tid & 63;
        qs[r][d] = qkv[base + (size_t)(t0 + r) * 3072 + h * 64 + d] * 0.125f;
    }
    __syncthreads();

    // scores: each thread handles k = tid, tid+256, ... for all 4 rows
    const float* Kp = qkv + base + 1024 + h * 64;
    for (int k = tid; k < T_; k += 256) {
        const float* kr = Kp + (size_t)k * 3072;
        float s0 = 0.f, s1 = 0.f, s2 = 0.f, s3 = 0.f;
#pragma unroll
        for (int d = 0; d < 64; d += 4) {
            float4 kv4 = *reinterpret_cast<const float4*>(kr + d);
            float4 q0 = *reinterpret_cast<const float4*>(&qs[0][d]);
            float4 q1 = *reinterpret_cast<const float4*>(&qs[1][d]);
            float4 q2 = *reinterpret_cast<const float4*>(&qs[2][d]);
            float4 q3 = *reinterpret_cast<const float4*>(&qs[3][d]);
            s0 += q0.x * kv4.x + q0.y * kv4.y + q0.z * kv4.z + q0.w * kv4.w;
            s1 += q1.x * kv4.x + q1.y * kv4.y + q1.z * kv4.z + q1.w * kv4.w;
            s2 += q2.x * kv4.x + q2.y * kv4.y + q2.z * kv4.z + q2.w * kv4.w;
            s3 += q3.x * kv4.x + q3.y * kv4.y + q3.z * kv4.z + q3.w * kv4.w;
        }
        sl[0][k] = s0; sl[1][k] = s1; sl[2][k] = s2; sl[3][k] = s3;
    }
    __syncthreads();

    {   // softmax: wave w owns row w
        const int w = tid >> 6, lane = tid & 63;
        float m = -INFINITY;
        for (int k = lane; k < T_; k += 64) m = fmaxf(m, sl[w][k]);
#pragma unroll
        for (int off = 32; off > 0; off >>= 1) m = fmaxf(m, __shfl_xor(m, off));
        float sum = 0.f;
        for (int k = lane; k < T_; k += 64) {
            float pv = expf(sl[w][k] - m);
            sl[w][k] = pv;
            sum += pv;
        }
#pragma unroll
        for (int off = 32; off > 0; off >>= 1) sum += __shfl_xor(sum, off);
        if (lane == 0) inv_s[w] = 1.0f / sum;
    }
    __syncthreads();

    {   // PV: thread (d = tid&63, part = tid>>6) accumulates k = part::4
        const int d = tid & 63, part = tid >> 6;
        const float* Vp = qkv + base + 2048 + h * 64 + d;
        float a0 = 0.f, a1 = 0.f, a2 = 0.f, a3 = 0.f;
        for (int k = part; k < T_; k += 4) {
            float v = Vp[(size_t)k * 3072];
            a0 += sl[0][k] * v; a1 += sl[1][k] * v;
            a2 += sl[2][k] * v; a3 += sl[3][k] * v;
        }
        red[0][part][d] = a0; red[1][part][d] = a1;
        red[2][part][d] = a2; red[3][part][d] = a3;
    }
    __syncthreads();

    {   // final reduce + write ctx in (b, t, h*64+d) layout
        const int r = tid >> 6, d = tid & 63;
        float o = (red[r][0][d] + red[r][1][d] + red[r][2][d] + red[r][3][d]) * inv_s[r];
        ctx[((size_t)b * T_ + t0 + r) * 1024 + h * 64 + d] = o;
    }
}

// ---------------------------------------------------------------------------
extern "C" void kernel_launch(void* const* d_in, const int* in_sizes, int n_in,
                              void* d_out, int out_size, void* d_ws, size_t ws_size,
                              hipStream_t stream) {
    const float* x     = (const float*)d_in[0];   // [2,2048,1024]
    const float* w_qkv = (const float*)d_in[1];   // [3072,1024]
    const float* w_out = (const float*)d_in[2];   // [1024,1024]
    const float* b_out = (const float*)d_in[3];   // [1024]
    float* out = (float*)d_out;                   // [2,2048,1024] f32

    char* ws = (char*)d_ws;
    float* qkv  = (float*)ws;                                     // 4096*3072 f32
    float* ctx  = (float*)(ws + (size_t)4096 * 3072 * 4);         // 4096*1024 f32
    float* cosT = (float*)(ws + (size_t)4096 * 3072 * 4 + (size_t)4096 * 1024 * 4);
    float* sinT = cosT + T_ * 32;

    rope_tables<<<256, 256, 0, stream>>>(cosT, sinT);
    gemm_bt<0><<<dim3(48, 64), 256, 0, stream>>>(x, w_qkv, nullptr, qkv, 4096, 3072, 1024);
    rope_apply<<<512, 256, 0, stream>>>(qkv, cosT, sinT);
    attn_kernel<<<dim3(512, 32), 256, 0, stream>>>(qkv, ctx);
    gemm_bt<1><<<dim3(16, 64), 256, 0, stream>>>(ctx, w_out, b_out, out, 4096, 1024, 1024);
}

// Round 3
// 683.259 us; speedup vs baseline: 11.5566x; 11.5566x over previous
//
#include <hip/hip_runtime.h>
#include <math.h>

#define B_ 2
#define T_ 2048
#define D_ 1024
#define H_ 16

typedef __attribute__((ext_vector_type(8))) short bf16x8;
typedef __attribute__((ext_vector_type(4))) float f32x4;

// ---------------------------------------------------------------------------
// helpers: fp32 -> bf16 (RNE) and pack
static __device__ inline unsigned f2bf_u16(float f) {
    union { float f; unsigned u; } v; v.f = f;
    return ((v.u + 0x7FFFu + ((v.u >> 16) & 1u)) >> 16) & 0xFFFFu;
}
static __device__ inline unsigned pack2bf(float lo, float hi) {
    return f2bf_u16(lo) | (f2bf_u16(hi) << 16);
}

// ---------------------------------------------------------------------------
// RoPE tables (unchanged)
__global__ __launch_bounds__(256) void rope_tables(float* __restrict__ cosT,
                                                   float* __restrict__ sinT) {
    int idx = blockIdx.x * 256 + threadIdx.x;
    int t = idx >> 5, i = idx & 31;
    double invf_d = exp(-((double)(2 * i) / 64.0) * 9.210340371976184);
    float invf = (float)invf_d;
    float ang = (float)t * invf;
    cosT[idx] = (float)cos((double)ang);
    sinT[idx] = (float)sin((double)ang);
}

// ---------------------------------------------------------------------------
// fp32 GEMM (unchanged this round)
template <int BIAS>
__global__ __launch_bounds__(256) void gemm_bt(const float* __restrict__ A,
                                               const float* __restrict__ Bm,
                                               const float* __restrict__ bias,
                                               float* __restrict__ C,
                                               int M, int N, int K) {
    __shared__ float As[16][64];
    __shared__ float Bs[16][64];
    const int tid = threadIdx.x;
    const int tx = tid & 15, ty = tid >> 4;
    const int m0 = blockIdx.y * 64, n0 = blockIdx.x * 64;
    const int lr = tid >> 2;
    const int lk = (tid & 3) << 2;
    float acc[4][4] = {};
    for (int k0 = 0; k0 < K; k0 += 16) {
        float4 a4 = *reinterpret_cast<const float4*>(&A[(size_t)(m0 + lr) * K + k0 + lk]);
        float4 b4 = *reinterpret_cast<const float4*>(&Bm[(size_t)(n0 + lr) * K + k0 + lk]);
        As[lk + 0][lr] = a4.x; As[lk + 1][lr] = a4.y;
        As[lk + 2][lr] = a4.z; As[lk + 3][lr] = a4.w;
        Bs[lk + 0][lr] = b4.x; Bs[lk + 1][lr] = b4.y;
        Bs[lk + 2][lr] = b4.z; Bs[lk + 3][lr] = b4.w;
        __syncthreads();
#pragma unroll
        for (int kk = 0; kk < 16; ++kk) {
            float4 av = *reinterpret_cast<const float4*>(&As[kk][ty << 2]);
            float4 bv = *reinterpret_cast<const float4*>(&Bs[kk][tx << 2]);
            float a_[4] = {av.x, av.y, av.z, av.w};
            float b_[4] = {bv.x, bv.y, bv.z, bv.w};
#pragma unroll
            for (int i = 0; i < 4; ++i)
#pragma unroll
                for (int j = 0; j < 4; ++j) acc[i][j] += a_[i] * b_[j];
        }
        __syncthreads();
    }
#pragma unroll
    for (int i = 0; i < 4; ++i) {
        int row = m0 + (ty << 2) + i;
        int col = n0 + (tx << 2);
        float4 o;
        o.x = acc[i][0]; o.y = acc[i][1]; o.z = acc[i][2]; o.w = acc[i][3];
        if (BIAS) {
            o.x += bias[col + 0]; o.y += bias[col + 1];
            o.z += bias[col + 2]; o.w += bias[col + 3];
        }
        *reinterpret_cast<float4*>(&C[(size_t)row * N + col]) = o;
    }
}

// ---------------------------------------------------------------------------
// RoPE apply (unchanged)
__global__ __launch_bounds__(256) void rope_apply(float* __restrict__ qkv,
                                                  const float* __restrict__ cosT,
                                                  const float* __restrict__ sinT) {
    int idx = blockIdx.x * 256 + threadIdx.x;
    int h = idx & 15;
    int sel = (idx >> 4) & 1;
    int t = (idx >> 5) & 2047;
    int b = idx >> 16;
    float* p = qkv + ((size_t)(b * T_ + t)) * 3072 + sel * 1024 + h * 64;
    float v[64];
#pragma unroll
    for (int d = 0; d < 64; d += 4) {
        float4 f = *reinterpret_cast<const float4*>(p + d);
        v[d] = f.x; v[d + 1] = f.y; v[d + 2] = f.z; v[d + 3] = f.w;
    }
    const float* c = cosT + t * 32;
    const float* s = sinT + t * 32;
    float o[64];
#pragma unroll
    for (int i = 0; i < 32; ++i) {
        float ci = c[i], si = s[i];
        o[i]      = v[i]      * ci - v[2 * i + 1] * si;
        o[i + 32] = v[i + 32] * ci + v[2 * i]     * si;
    }
#pragma unroll
    for (int d = 0; d < 64; d += 4) {
        float4 f;
        f.x = o[d]; f.y = o[d + 1]; f.z = o[d + 2]; f.w = o[d + 3];
        *reinterpret_cast<float4*>(p + d) = f;
    }
}

// ---------------------------------------------------------------------------
// Staging helpers for flash attention.
// Row-major 64x64 f32 tile (row stride 3072) -> bf16 LDS [64][64] with XOR
// swizzle: byte_in_row ^= (row&7)<<4.  (G4 fix; write & read both swizzled.)
static __device__ inline void stage_rowmajor(char* lds, const float* g,
                                             float scale, int tid) {
#pragma unroll
    for (int i = 0; i < 4; ++i) {
        int idx = tid + 256 * i;          // 0..1023
        int row = idx >> 4, c = idx & 15; // c = float4 index within row
        float4 f = *reinterpret_cast<const float4*>(g + (size_t)row * 3072 + c * 4);
        unsigned lo = pack2bf(f.x * scale, f.y * scale);
        unsigned hi = pack2bf(f.z * scale, f.w * scale);
        int byte = row * 128 + ((c * 8) ^ ((row & 7) << 4));
        *reinterpret_cast<unsigned long long*>(lds + byte) =
            (unsigned long long)lo | ((unsigned long long)hi << 32);
    }
}

// V tile 64(kv)x64(n) f32 -> TRANSPOSED bf16 LDS vt[n][kv], same swizzle.
static __device__ inline void stage_v_t(char* lds, const float* g, int tid) {
    int c = tid & 15, r = tid >> 4;      // n0 = 4c, kv0 = 4r
    int n0 = c * 4, kv0 = r * 4;
    float4 f0 = *reinterpret_cast<const float4*>(g + (size_t)(kv0 + 0) * 3072 + n0);
    float4 f1 = *reinterpret_cast<const float4*>(g + (size_t)(kv0 + 1) * 3072 + n0);
    float4 f2 = *reinterpret_cast<const float4*>(g + (size_t)(kv0 + 2) * 3072 + n0);
    float4 f3 = *reinterpret_cast<const float4*>(g + (size_t)(kv0 + 3) * 3072 + n0);
    const float* a0 = &f0.x; const float* a1 = &f1.x;
    const float* a2 = &f2.x; const float* a3 = &f3.x;
#pragma unroll
    for (int j = 0; j < 4; ++j) {
        int n = n0 + j;
        unsigned lo = pack2bf(a0[j], a1[j]);   // kv0, kv0+1
        unsigned hi = pack2bf(a2[j], a3[j]);   // kv0+2, kv0+3
        int byte = n * 128 + ((kv0 * 2) ^ ((n & 7) << 4));
        *reinterpret_cast<unsigned long long*>(lds + byte) =
            (unsigned long long)lo | ((unsigned long long)hi << 32);
    }
}

// swizzled 16B fragment read: row-major [64][64] bf16, 8 contiguous elems
static __device__ inline bf16x8 frag_read(const char* lds, int row, int elem0) {
    int byte = row * 128 + ((elem0 * 2) ^ ((row & 7) << 4));
    return *reinterpret_cast<const bf16x8*>(lds + byte);
}

// ---------------------------------------------------------------------------
// Flash attention, bf16 MFMA, swapped-QK^T orientation.
// Grid: (T/64, B*H). Block: 256 threads = 4 waves; wave w owns q rows
// [qb*64 + 16w, +16). Layouts per guide §3 (16x16x32_bf16):
//   A: row = lane&15, k = 8*(lane>>4)+j (contiguous 8)
//   B: col = lane&15, k = 8*(lane>>4)+j
//   C/D: col = lane&15, row = (lane>>4)*4 + reg   [m89-verified]
__global__ __launch_bounds__(256) void attn_mfma(const float* __restrict__ qkv,
                                                 float* __restrict__ ctx) {
    __shared__ unsigned long long ldsbuf[3072];   // 24 KB
    char* q_lds  = (char*)ldsbuf;                 // 8 KB
    char* k_lds  = q_lds + 8192;                  // 8 KB
    char* vt_lds = q_lds + 16384;                 // 8 KB

    const int tid  = threadIdx.x;
    const int w    = tid >> 6;
    const int lane = tid & 63;
    const int g    = lane >> 4;
    const int q    = lane & 15;

    const int qb = blockIdx.x;           // 0..31
    const int bh = blockIdx.y;           // 0..31
    const int b  = bh >> 4, h = bh & 15;

    const float* base = qkv + (size_t)b * T_ * 3072;
    const float* Qg = base + (size_t)(qb * 64) * 3072 + h * 64;
    const float* Kg = base + 1024 + h * 64;
    const float* Vg = base + 2048 + h * 64;

    stage_rowmajor(q_lds, Qg, 0.125f, tid);
    stage_rowmajor(k_lds, Kg, 1.0f, tid);
    stage_v_t(vt_lds, Vg, tid);
    __syncthreads();

    // Q fragments (B operand): col q = 16w + lane&15, d = 8g+j (+32 per kstep)
    const int qrow = 16 * w + q;
    bf16x8 bq0 = frag_read(q_lds, qrow, 8 * g);
    bf16x8 bq1 = frag_read(q_lds, qrow, 32 + 8 * g);

    f32x4 acc[4];
#pragma unroll
    for (int i = 0; i < 4; ++i) acc[i] = (f32x4){0.f, 0.f, 0.f, 0.f};
    float mrun = -INFINITY, lrun = 0.f;

    const int srcA = q + 32 * (g & 1);
    const int srcB = srcA + 16;
    const bool hiSel = (g >> 1) != 0;

    for (int kt = 0; kt < 32; ++kt) {
        // ---- S^T = K . Q^T : 4 mtiles (kv) x 2 ksteps (d)
        f32x4 st[4];
#pragma unroll
        for (int mt = 0; mt < 4; ++mt) {
            int kvrow = 16 * mt + q;
            f32x4 c = (f32x4){0.f, 0.f, 0.f, 0.f};
            c = __builtin_amdgcn_mfma_f32_16x16x32_bf16(
                    frag_read(k_lds, kvrow, 8 * g), bq0, c, 0, 0, 0);
            c = __builtin_amdgcn_mfma_f32_16x16x32_bf16(
                    frag_read(k_lds, kvrow, 32 + 8 * g), bq1, c, 0, 0, 0);
            st[mt] = c;   // S^T[kv=16mt+4g+r][q], q = lane&15
        }

        // ---- online softmax (per-lane q-row; groups merged by shfl 16,32)
        float tmax = -INFINITY;
#pragma unroll
        for (int mt = 0; mt < 4; ++mt)
#pragma unroll
            for (int r = 0; r < 4; ++r) tmax = fmaxf(tmax, st[mt][r]);
        tmax = fmaxf(tmax, __shfl_xor(tmax, 16));
        tmax = fmaxf(tmax, __shfl_xor(tmax, 32));
        float mnew = fmaxf(mrun, tmax);
        float corr = __expf(mrun - mnew);
        mrun = mnew;

        float p[16];
        float tsum = 0.f;
#pragma unroll
        for (int mt = 0; mt < 4; ++mt)
#pragma unroll
            for (int r = 0; r < 4; ++r) {
                float e = __expf(st[mt][r] - mnew);
                p[4 * mt + r] = e;
                tsum += e;
            }
        tsum += __shfl_xor(tsum, 16);
        tsum += __shfl_xor(tsum, 32);
        lrun = lrun * corr + tsum;
#pragma unroll
        for (int i = 0; i < 4; ++i) {
            acc[i][0] *= corr; acc[i][1] *= corr;
            acc[i][2] *= corr; acc[i][3] *= corr;
        }

        // ---- P^T (C/D layout) -> PV B-fragments via register shuffle
        unsigned pk0[4], pk1[4];
#pragma unroll
        for (int mt = 0; mt < 4; ++mt) {
            pk0[mt] = pack2bf(p[4 * mt + 0], p[4 * mt + 1]); // kv 16mt+4g+{0,1}
            pk1[mt] = pack2bf(p[4 * mt + 2], p[4 * mt + 3]); // kv 16mt+4g+{2,3}
        }
        union { bf16x8 v; unsigned u[4]; } bp0, bp1;
        {   // kstep 0: kv 0..31 (mtiles 0,1)
            unsigned xa0 = __shfl(pk0[0], srcA), ya0 = __shfl(pk0[1], srcA);
            unsigned xa1 = __shfl(pk1[0], srcA), ya1 = __shfl(pk1[1], srcA);
            unsigned xb0 = __shfl(pk0[0], srcB), yb0 = __shfl(pk0[1], srcB);
            unsigned xb1 = __shfl(pk1[0], srcB), yb1 = __shfl(pk1[1], srcB);
            bp0.u[0] = hiSel ? ya0 : xa0;
            bp0.u[1] = hiSel ? ya1 : xa1;
            bp0.u[2] = hiSel ? yb0 : xb0;
            bp0.u[3] = hiSel ? yb1 : xb1;
        }
        {   // kstep 1: kv 32..63 (mtiles 2,3)
            unsigned xa0 = __shfl(pk0[2], srcA), ya0 = __shfl(pk0[3], srcA);
            unsigned xa1 = __shfl(pk1[2], srcA), ya1 = __shfl(pk1[3], srcA);
            unsigned xb0 = __shfl(pk0[2], srcB), yb0 = __shfl(pk0[3], srcB);
            unsigned xb1 = __shfl(pk1[2], srcB), yb1 = __shfl(pk1[3], srcB);
            bp1.u[0] = hiSel ? ya0 : xa0;
            bp1.u[1] = hiSel ? ya1 : xa1;
            bp1.u[2] = hiSel ? yb0 : xb0;
            bp1.u[3] = hiSel ? yb1 : xb1;
        }

        // ---- O^T += V^T . P^T : 4 ntiles x 2 ksteps
#pragma unroll
        for (int nt = 0; nt < 4; ++nt) {
            int nrow = 16 * nt + q;
            acc[nt] = __builtin_amdgcn_mfma_f32_16x16x32_bf16(
                          frag_read(vt_lds, nrow, 8 * g), bp0.v, acc[nt], 0, 0, 0);
            acc[nt] = __builtin_amdgcn_mfma_f32_16x16x32_bf16(
                          frag_read(vt_lds, nrow, 32 + 8 * g), bp1.v, acc[nt], 0, 0, 0);
        }

        __syncthreads();                 // all waves done reading tile kt
        if (kt < 31) {
            stage_rowmajor(k_lds, Kg + (size_t)(kt + 1) * 64 * 3072, 1.0f, tid);
            stage_v_t(vt_lds, Vg + (size_t)(kt + 1) * 64 * 3072, tid);
            __syncthreads();             // writes visible before next compute
        }
    }

    // ---- write O = acc/l : lane holds q = qb*64+16w+(lane&15), n = 16nt+4g+r
    float inv_l = 1.0f / lrun;
    const int q_abs = qb * 64 + 16 * w + q;
    float* outp = ctx + ((size_t)b * T_ + q_abs) * 1024 + h * 64;
#pragma unroll
    for (int nt = 0; nt < 4; ++nt)
#pragma unroll
        for (int r = 0; r < 4; ++r)
            outp[16 * nt + 4 * g + r] = acc[nt][r] * inv_l;
}

// ---------------------------------------------------------------------------
extern "C" void kernel_launch(void* const* d_in, const int* in_sizes, int n_in,
                              void* d_out, int out_size, void* d_ws, size_t ws_size,
                              hipStream_t stream) {
    const float* x     = (const float*)d_in[0];
    const float* w_qkv = (const float*)d_in[1];
    const float* w_out = (const float*)d_in[2];
    const float* b_out = (const float*)d_in[3];
    float* out = (float*)d_out;

    char* ws = (char*)d_ws;
    float* qkv  = (float*)ws;
    float* ctx  = (float*)(ws + (size_t)4096 * 3072 * 4);
    float* cosT = (float*)(ws + (size_t)4096 * 3072 * 4 + (size_t)4096 * 1024 * 4);
    float* sinT = cosT + T_ * 32;

    rope_tables<<<256, 256, 0, stream>>>(cosT, sinT);
    gemm_bt<0><<<dim3(48, 64), 256, 0, stream>>>(x, w_qkv, nullptr, qkv, 4096, 3072, 1024);
    rope_apply<<<512, 256, 0, stream>>>(qkv, cosT, sinT);
    attn_mfma<<<dim3(32, 32), 256, 0, stream>>>(qkv, ctx);
    gemm_bt<1><<<dim3(16, 64), 256, 0, stream>>>(ctx, w_out, b_out, out, 4096, 1024, 1024);
}

// Round 4
// 349.979 us; speedup vs baseline: 22.5617x; 1.9523x over previous
//
#include <hip/hip_runtime.h>
#include <math.h>

#define B_ 2
#define T_ 2048
#define D_ 1024
#define H_ 16

typedef __attribute__((ext_vector_type(8))) short bf16x8;
typedef __attribute__((ext_vector_type(4))) float f32x4;
typedef __attribute__((address_space(3))) char lds_char;
typedef __attribute__((address_space(1))) const char g_char;

// ---------------------------------------------------------------------------
static __device__ inline unsigned short bf16_rne(float f) {
    union { float f; unsigned u; } v; v.f = f;
    unsigned r = v.u + 0x7FFFu + ((v.u >> 16) & 1u);
    return (unsigned short)(r >> 16);
}
static __device__ inline unsigned pack2bf(float lo, float hi) {
    return (unsigned)bf16_rne(lo) | ((unsigned)bf16_rne(hi) << 16);
}

// ---------------------------------------------------------------------------
// Split fp32 -> (hi, lo) bf16 planes.  hi = rne(f); lo = rne(f - hi).
__global__ __launch_bounds__(256) void split_kernel(const float* __restrict__ in,
                                                    unsigned short* __restrict__ hi,
                                                    unsigned short* __restrict__ lo,
                                                    int n8) {
    int i = blockIdx.x * 256 + threadIdx.x;
    if (i >= n8) return;
    const float4* ip = (const float4*)in + (size_t)i * 2;
    float4 f0 = ip[0], f1 = ip[1];
    float fs[8] = {f0.x, f0.y, f0.z, f0.w, f1.x, f1.y, f1.z, f1.w};
    unsigned hu[4], lu[4];
#pragma unroll
    for (int j = 0; j < 4; ++j) {
        unsigned short h0 = bf16_rne(fs[2 * j]), h1 = bf16_rne(fs[2 * j + 1]);
        union { unsigned u; float f; } c0, c1;
        c0.u = (unsigned)h0 << 16; c1.u = (unsigned)h1 << 16;
        unsigned short l0 = bf16_rne(fs[2 * j] - c0.f);
        unsigned short l1 = bf16_rne(fs[2 * j + 1] - c1.f);
        hu[j] = (unsigned)h0 | ((unsigned)h1 << 16);
        lu[j] = (unsigned)l0 | ((unsigned)l1 << 16);
    }
    *(uint4*)(hi + (size_t)i * 8) = make_uint4(hu[0], hu[1], hu[2], hu[3]);
    *(uint4*)(lo + (size_t)i * 8) = make_uint4(lu[0], lu[1], lu[2], lu[3]);
}

// ---------------------------------------------------------------------------
// RoPE tables (unchanged)
__global__ __launch_bounds__(256) void rope_tables(float* __restrict__ cosT,
                                                   float* __restrict__ sinT) {
    int idx = blockIdx.x * 256 + threadIdx.x;
    int t = idx >> 5, i = idx & 31;
    double invf_d = exp(-((double)(2 * i) / 64.0) * 9.210340371976184);
    float invf = (float)invf_d;
    float ang = (float)t * invf;
    cosT[idx] = (float)cos((double)ang);
    sinT[idx] = (float)sin((double)ang);
}

// ---------------------------------------------------------------------------
// RoPE apply (unchanged)
__global__ __launch_bounds__(256) void rope_apply(float* __restrict__ qkv,
                                                  const float* __restrict__ cosT,
                                                  const float* __restrict__ sinT) {
    int idx = blockIdx.x * 256 + threadIdx.x;
    int h = idx & 15;
    int sel = (idx >> 4) & 1;
    int t = (idx >> 5) & 2047;
    int b = idx >> 16;
    float* p = qkv + ((size_t)(b * T_ + t)) * 3072 + sel * 1024 + h * 64;
    float v[64];
#pragma unroll
    for (int d = 0; d < 64; d += 4) {
        float4 f = *reinterpret_cast<const float4*>(p + d);
        v[d] = f.x; v[d + 1] = f.y; v[d + 2] = f.z; v[d + 3] = f.w;
    }
    const float* c = cosT + t * 32;
    const float* s = sinT + t * 32;
    float o[64];
#pragma unroll
    for (int i = 0; i < 32; ++i) {
        float ci = c[i], si = s[i];
        o[i]      = v[i]      * ci - v[2 * i + 1] * si;
        o[i + 32] = v[i + 32] * ci + v[2 * i]     * si;
    }
#pragma unroll
    for (int d = 0; d < 64; d += 4) {
        float4 f;
        f.x = o[d]; f.y = o[d + 1]; f.z = o[d + 2]; f.w = o[d + 3];
        *reinterpret_cast<float4*>(p + d) = f;
    }
}

// ---------------------------------------------------------------------------
// Split-bf16 GEMM: C[M,N] = A[M,K] @ Bm[N,K]^T (+bias), 3-term hi/lo MFMA.
// 128x128 tile, 4 waves (64x64 quadrant each), BK=32, global_load_lds
// staging with pre-swizzled source (granule ^= row&3), swizzled ds_read.
template <int BIAS>
__global__ __launch_bounds__(256) void gemm_split(const unsigned short* __restrict__ Ahi,
                                                  const unsigned short* __restrict__ Alo,
                                                  const unsigned short* __restrict__ Bhi,
                                                  const unsigned short* __restrict__ Blo,
                                                  const float* __restrict__ bias,
                                                  float* __restrict__ C,
                                                  int M, int N, int K) {
    __shared__ alignas(16) char lds[32768];      // 4 planes x [128][32] bf16
    char* As_hi = lds;
    char* As_lo = lds + 8192;
    char* Bs_hi = lds + 16384;
    char* Bs_lo = lds + 24576;

    const int tid = threadIdx.x, l = tid & 63, w = tid >> 6;
    const int m0 = blockIdx.y * 128, n0 = blockIdx.x * 128;
    const int wr = (w >> 1) * 64, wc = (w & 1) * 64;
    const int q16 = l & 15, g8 = l >> 4;
    const int srow = w * 16 + (l >> 2);          // staging row (rd adds 64)

    f32x4 acc[4][4];
#pragma unroll
    for (int i = 0; i < 4; ++i)
#pragma unroll
        for (int j = 0; j < 4; ++j) acc[i][j] = (f32x4){0.f, 0.f, 0.f, 0.f};

    for (int k0 = 0; k0 < K; k0 += 32) {
        // ---- stage 4 planes (pre-swizzled global source, linear LDS dest)
#pragma unroll
        for (int rd = 0; rd < 2; ++rd) {
            int row = srow + rd * 64;
            int g = (l & 3) ^ (row & 3);
            size_t goffA = (size_t)(m0 + row) * K + k0 + g * 8;
            size_t goffB = (size_t)(n0 + row) * K + k0 + g * 8;
            int lbase = rd * 4096 + w * 1024;
            __builtin_amdgcn_global_load_lds((g_char*)(Ahi + goffA), (lds_char*)(As_hi + lbase), 16, 0, 0);
            __builtin_amdgcn_global_load_lds((g_char*)(Alo + goffA), (lds_char*)(As_lo + lbase), 16, 0, 0);
            __builtin_amdgcn_global_load_lds((g_char*)(Bhi + goffB), (lds_char*)(Bs_hi + lbase), 16, 0, 0);
            __builtin_amdgcn_global_load_lds((g_char*)(Blo + goffB), (lds_char*)(Bs_lo + lbase), 16, 0, 0);
        }
        __syncthreads();                         // drains vmcnt before compute

        bf16x8 ah[4], al[4], bh[4], bl[4];
#pragma unroll
        for (int i = 0; i < 4; ++i) {
            int ra = wr + 16 * i + q16, rb = wc + 16 * i + q16;
            ah[i] = *(const bf16x8*)(As_hi + ra * 64 + ((g8 ^ (ra & 3)) * 16));
            al[i] = *(const bf16x8*)(As_lo + ra * 64 + ((g8 ^ (ra & 3)) * 16));
            bh[i] = *(const bf16x8*)(Bs_hi + rb * 64 + ((g8 ^ (rb & 3)) * 16));
            bl[i] = *(const bf16x8*)(Bs_lo + rb * 64 + ((g8 ^ (rb & 3)) * 16));
        }
#pragma unroll
        for (int i = 0; i < 4; ++i)
#pragma unroll
            for (int j = 0; j < 4; ++j) {
                acc[i][j] = __builtin_amdgcn_mfma_f32_16x16x32_bf16(ah[i], bh[j], acc[i][j], 0, 0, 0);
                acc[i][j] = __builtin_amdgcn_mfma_f32_16x16x32_bf16(ah[i], bl[j], acc[i][j], 0, 0, 0);
                acc[i][j] = __builtin_amdgcn_mfma_f32_16x16x32_bf16(al[i], bh[j], acc[i][j], 0, 0, 0);
            }
        __syncthreads();                         // all reads done before next stage
    }

    // ---- epilogue: C/D layout col=lane&15, row=4*(lane>>4)+r  [m89]
#pragma unroll
    for (int i = 0; i < 4; ++i)
#pragma unroll
        for (int j = 0; j < 4; ++j) {
            int col = n0 + wc + 16 * j + q16;
            float badd = BIAS ? bias[col] : 0.f;
#pragma unroll
            for (int r = 0; r < 4; ++r) {
                int row = m0 + wr + 16 * i + 4 * g8 + r;
                C[(size_t)row * N + col] = acc[i][j][r] + badd;
            }
        }
}

// ---------------------------------------------------------------------------
// Flash attention (unchanged from round 3)
static __device__ inline void stage_rowmajor(char* lds, const float* g,
                                             float scale, int tid) {
#pragma unroll
    for (int i = 0; i < 4; ++i) {
        int idx = tid + 256 * i;
        int row = idx >> 4, c = idx & 15;
        float4 f = *reinterpret_cast<const float4*>(g + (size_t)row * 3072 + c * 4);
        unsigned lo = pack2bf(f.x * scale, f.y * scale);
        unsigned hi = pack2bf(f.z * scale, f.w * scale);
        int byte = row * 128 + ((c * 8) ^ ((row & 7) << 4));
        *reinterpret_cast<unsigned long long*>(lds + byte) =
            (unsigned long long)lo | ((unsigned long long)hi << 32);
    }
}

static __device__ inline void stage_v_t(char* lds, const float* g, int tid) {
    int c = tid & 15, r = tid >> 4;
    int n0 = c * 4, kv0 = r * 4;
    float4 f0 = *reinterpret_cast<const float4*>(g + (size_t)(kv0 + 0) * 3072 + n0);
    float4 f1 = *reinterpret_cast<const float4*>(g + (size_t)(kv0 + 1) * 3072 + n0);
    float4 f2 = *reinterpret_cast<const float4*>(g + (size_t)(kv0 + 2) * 3072 + n0);
    float4 f3 = *reinterpret_cast<const float4*>(g + (size_t)(kv0 + 3) * 3072 + n0);
    const float* a0 = &f0.x; const float* a1 = &f1.x;
    const float* a2 = &f2.x; const float* a3 = &f3.x;
#pragma unroll
    for (int j = 0; j < 4; ++j) {
        int n = n0 + j;
        unsigned lo = pack2bf(a0[j], a1[j]);
        unsigned hi = pack2bf(a2[j], a3[j]);
        int byte = n * 128 + ((kv0 * 2) ^ ((n & 7) << 4));
        *reinterpret_cast<unsigned long long*>(lds + byte) =
            (unsigned long long)lo | ((unsigned long long)hi << 32);
    }
}

static __device__ inline bf16x8 frag_read(const char* lds, int row, int elem0) {
    int byte = row * 128 + ((elem0 * 2) ^ ((row & 7) << 4));
    return *reinterpret_cast<const bf16x8*>(lds + byte);
}

__global__ __launch_bounds__(256) void attn_mfma(const float* __restrict__ qkv,
                                                 float* __restrict__ ctx) {
    __shared__ unsigned long long ldsbuf[3072];
    char* q_lds  = (char*)ldsbuf;
    char* k_lds  = q_lds + 8192;
    char* vt_lds = q_lds + 16384;

    const int tid  = threadIdx.x;
    const int w    = tid >> 6;
    const int lane = tid & 63;
    const int g    = lane >> 4;
    const int q    = lane & 15;

    const int qb = blockIdx.x;
    const int bh = blockIdx.y;
    const int b  = bh >> 4, h = bh & 15;

    const float* base = qkv + (size_t)b * T_ * 3072;
    const float* Qg = base + (size_t)(qb * 64) * 3072 + h * 64;
    const float* Kg = base + 1024 + h * 64;
    const float* Vg = base + 2048 + h * 64;

    stage_rowmajor(q_lds, Qg, 0.125f, tid);
    stage_rowmajor(k_lds, Kg, 1.0f, tid);
    stage_v_t(vt_lds, Vg, tid);
    __syncthreads();

    const int qrow = 16 * w + q;
    bf16x8 bq0 = frag_read(q_lds, qrow, 8 * g);
    bf16x8 bq1 = frag_read(q_lds, qrow, 32 + 8 * g);

    f32x4 acc[4];
#pragma unroll
    for (int i = 0; i < 4; ++i) acc[i] = (f32x4){0.f, 0.f, 0.f, 0.f};
    float mrun = -INFINITY, lrun = 0.f;

    const int srcA = q + 32 * (g & 1);
    const int srcB = srcA + 16;
    const bool hiSel = (g >> 1) != 0;

    for (int kt = 0; kt < 32; ++kt) {
        f32x4 st[4];
#pragma unroll
        for (int mt = 0; mt < 4; ++mt) {
            int kvrow = 16 * mt + q;
            f32x4 c = (f32x4){0.f, 0.f, 0.f, 0.f};
            c = __builtin_amdgcn_mfma_f32_16x16x32_bf16(
                    frag_read(k_lds, kvrow, 8 * g), bq0, c, 0, 0, 0);
            c = __builtin_amdgcn_mfma_f32_16x16x32_bf16(
                    frag_read(k_lds, kvrow, 32 + 8 * g), bq1, c, 0, 0, 0);
            st[mt] = c;
        }

        float tmax = -INFINITY;
#pragma unroll
        for (int mt = 0; mt < 4; ++mt)
#pragma unroll
            for (int r = 0; r < 4; ++r) tmax = fmaxf(tmax, st[mt][r]);
        tmax = fmaxf(tmax, __shfl_xor(tmax, 16));
        tmax = fmaxf(tmax, __shfl_xor(tmax, 32));
        float mnew = fmaxf(mrun, tmax);
        float corr = __expf(mrun - mnew);
        mrun = mnew;

        float p[16];
        float tsum = 0.f;
#pragma unroll
        for (int mt = 0; mt < 4; ++mt)
#pragma unroll
            for (int r = 0; r < 4; ++r) {
                float e = __expf(st[mt][r] - mnew);
                p[4 * mt + r] = e;
                tsum += e;
            }
        tsum += __shfl_xor(tsum, 16);
        tsum += __shfl_xor(tsum, 32);
        lrun = lrun * corr + tsum;
#pragma unroll
        for (int i = 0; i < 4; ++i) {
            acc[i][0] *= corr; acc[i][1] *= corr;
            acc[i][2] *= corr; acc[i][3] *= corr;
        }

        unsigned pk0[4], pk1[4];
#pragma unroll
        for (int mt = 0; mt < 4; ++mt) {
            pk0[mt] = pack2bf(p[4 * mt + 0], p[4 * mt + 1]);
            pk1[mt] = pack2bf(p[4 * mt + 2], p[4 * mt + 3]);
        }
        union { bf16x8 v; unsigned u[4]; } bp0, bp1;
        {
            unsigned xa0 = __shfl(pk0[0], srcA), ya0 = __shfl(pk0[1], srcA);
            unsigned xa1 = __shfl(pk1[0], srcA), ya1 = __shfl(pk1[1], srcA);
            unsigned xb0 = __shfl(pk0[0], srcB), yb0 = __shfl(pk0[1], srcB);
            unsigned xb1 = __shfl(pk1[0], srcB), yb1 = __shfl(pk1[1], srcB);
            bp0.u[0] = hiSel ? ya0 : xa0;
            bp0.u[1] = hiSel ? ya1 : xa1;
            bp0.u[2] = hiSel ? yb0 : xb0;
            bp0.u[3] = hiSel ? yb1 : xb1;
        }
        {
            unsigned xa0 = __shfl(pk0[2], srcA), ya0 = __shfl(pk0[3], srcA);
            unsigned xa1 = __shfl(pk1[2], srcA), ya1 = __shfl(pk1[3], srcA);
            unsigned xb0 = __shfl(pk0[2], srcB), yb0 = __shfl(pk0[3], srcB);
            unsigned xb1 = __shfl(pk1[2], srcB), yb1 = __shfl(pk1[3], srcB);
            bp1.u[0] = hiSel ? ya0 : xa0;
            bp1.u[1] = hiSel ? ya1 : xa1;
            bp1.u[2] = hiSel ? yb0 : xb0;
            bp1.u[3] = hiSel ? yb1 : xb1;
        }

#pragma unroll
        for (int nt = 0; nt < 4; ++nt) {
            int nrow = 16 * nt + q;
            acc[nt] = __builtin_amdgcn_mfma_f32_16x16x32_bf16(
                          frag_read(vt_lds, nrow, 8 * g), bp0.v, acc[nt], 0, 0, 0);
            acc[nt] = __builtin_amdgcn_mfma_f32_16x16x32_bf16(
                          frag_read(vt_lds, nrow, 32 + 8 * g), bp1.v, acc[nt], 0, 0, 0);
        }

        __syncthreads();
        if (kt < 31) {
            stage_rowmajor(k_lds, Kg + (size_t)(kt + 1) * 64 * 3072, 1.0f, tid);
            stage_v_t(vt_lds, Vg + (size_t)(kt + 1) * 64 * 3072, tid);
            __syncthreads();
        }
    }

    float inv_l = 1.0f / lrun;
    const int q_abs = qb * 64 + 16 * w + q;
    float* outp = ctx + ((size_t)b * T_ + q_abs) * 1024 + h * 64;
#pragma unroll
    for (int nt = 0; nt < 4; ++nt)
#pragma unroll
        for (int r = 0; r < 4; ++r)
            outp[16 * nt + 4 * g + r] = acc[nt][r] * inv_l;
}

// ---------------------------------------------------------------------------
extern "C" void kernel_launch(void* const* d_in, const int* in_sizes, int n_in,
                              void* d_out, int out_size, void* d_ws, size_t ws_size,
                              hipStream_t stream) {
    const float* x     = (const float*)d_in[0];   // [2,2048,1024]
    const float* w_qkv = (const float*)d_in[1];   // [3072,1024]
    const float* w_out = (const float*)d_in[2];   // [1024,1024]
    const float* b_out = (const float*)d_in[3];   // [1024]
    float* out = (float*)d_out;

    char* base = (char*)d_ws;
    // Region 0 [0, 50.33 MB): qkv fp32; after attn reused for ctx/wout planes
    float* qkvF = (float*)base;
    unsigned short* ctx_hi  = (unsigned short*)(base + 0);
    unsigned short* ctx_lo  = (unsigned short*)(base + 8388608);
    unsigned short* wout_hi = (unsigned short*)(base + 16777216);
    unsigned short* wout_lo = (unsigned short*)(base + 18874368);
    // Region 1 [50.33, 67.1 MB): x planes during qkv-gemm; ctx fp32 after
    unsigned short* x_hi = (unsigned short*)(base + 50331648);
    unsigned short* x_lo = (unsigned short*)(base + 58720256);
    float* ctxF = (float*)(base + 50331648);
    // Region 2 [67.1, 79.7 MB): w_qkv planes
    unsigned short* wq_hi = (unsigned short*)(base + 67108864);
    unsigned short* wq_lo = (unsigned short*)(base + 73400320);
    // Region 3: tables
    float* cosT = (float*)(base + 79691776);
    float* sinT = cosT + 65536;

    rope_tables<<<256, 256, 0, stream>>>(cosT, sinT);
    split_kernel<<<2048, 256, 0, stream>>>(x, x_hi, x_lo, 524288);
    split_kernel<<<1536, 256, 0, stream>>>(w_qkv, wq_hi, wq_lo, 393216);
    gemm_split<0><<<dim3(24, 32), 256, 0, stream>>>(x_hi, x_lo, wq_hi, wq_lo,
                                                    nullptr, qkvF, 4096, 3072, 1024);
    rope_apply<<<512, 256, 0, stream>>>(qkvF, cosT, sinT);
    attn_mfma<<<dim3(32, 32), 256, 0, stream>>>(qkvF, ctxF);
    split_kernel<<<2048, 256, 0, stream>>>(ctxF, ctx_hi, ctx_lo, 524288);
    split_kernel<<<512, 256, 0, stream>>>(w_out, wout_hi, wout_lo, 131072);
    gemm_split<1><<<dim3(8, 32), 256, 0, stream>>>(ctx_hi, ctx_lo, wout_hi, wout_lo,
                                                   b_out, out, 4096, 1024, 1024);
}

// Round 6
// 324.752 us; speedup vs baseline: 24.3143x; 1.0777x over previous
//
#include <hip/hip_runtime.h>
#include <math.h>

#define B_ 2
#define T_ 2048
#define D_ 1024
#define H_ 16

typedef __attribute__((ext_vector_type(8))) short bf16x8;
typedef __attribute__((ext_vector_type(4))) float f32x4;
typedef __attribute__((address_space(3))) char lds_char;
typedef __attribute__((address_space(1))) const char g_char;

// 0.125 * log2(e): folds the 1/sqrt(64) score scale + exp->exp2 rebase into Q.
#define QSCALE 0.18033688011112042f
#define DEFER_THR 11.5f   // 8 nats in log2 units (T13)

// ---------------------------------------------------------------------------
static __device__ inline unsigned short bf16_rne(float f) {
    union { float f; unsigned u; } v; v.f = f;
    unsigned r = v.u + 0x7FFFu + ((v.u >> 16) & 1u);
    return (unsigned short)(r >> 16);
}
static __device__ inline unsigned pack2bf(float lo, float hi) {
    return (unsigned)bf16_rne(lo) | ((unsigned)bf16_rne(hi) << 16);
}

// ---------------------------------------------------------------------------
// Split fp32 -> (hi, lo) bf16 planes.  hi = rne(f); lo = rne(f - hi).
__global__ __launch_bounds__(256) void split_kernel(const float* __restrict__ in,
                                                    unsigned short* __restrict__ hi,
                                                    unsigned short* __restrict__ lo,
                                                    int n8) {
    int i = blockIdx.x * 256 + threadIdx.x;
    if (i >= n8) return;
    const float4* ip = (const float4*)in + (size_t)i * 2;
    float4 f0 = ip[0], f1 = ip[1];
    float fs[8] = {f0.x, f0.y, f0.z, f0.w, f1.x, f1.y, f1.z, f1.w};
    unsigned hu[4], lu[4];
#pragma unroll
    for (int j = 0; j < 4; ++j) {
        unsigned short h0 = bf16_rne(fs[2 * j]), h1 = bf16_rne(fs[2 * j + 1]);
        union { unsigned u; float f; } c0, c1;
        c0.u = (unsigned)h0 << 16; c1.u = (unsigned)h1 << 16;
        unsigned short l0 = bf16_rne(fs[2 * j] - c0.f);
        unsigned short l1 = bf16_rne(fs[2 * j + 1] - c1.f);
        hu[j] = (unsigned)h0 | ((unsigned)h1 << 16);
        lu[j] = (unsigned)l0 | ((unsigned)l1 << 16);
    }
    *(uint4*)(hi + (size_t)i * 8) = make_uint4(hu[0], hu[1], hu[2], hu[3]);
    *(uint4*)(lo + (size_t)i * 8) = make_uint4(lu[0], lu[1], lu[2], lu[3]);
}

// ---------------------------------------------------------------------------
// RoPE tables (unchanged)
__global__ __launch_bounds__(256) void rope_tables(float* __restrict__ cosT,
                                                   float* __restrict__ sinT) {
    int idx = blockIdx.x * 256 + threadIdx.x;
    int t = idx >> 5, i = idx & 31;
    double invf_d = exp(-((double)(2 * i) / 64.0) * 9.210340371976184);
    float invf = (float)invf_d;
    float ang = (float)t * invf;
    cosT[idx] = (float)cos((double)ang);
    sinT[idx] = (float)sin((double)ang);
}

// ---------------------------------------------------------------------------
// Split-bf16 GEMM (unchanged from round 4)
template <int BIAS>
__global__ __launch_bounds__(256) void gemm_split(const unsigned short* __restrict__ Ahi,
                                                  const unsigned short* __restrict__ Alo,
                                                  const unsigned short* __restrict__ Bhi,
                                                  const unsigned short* __restrict__ Blo,
                                                  const float* __restrict__ bias,
                                                  float* __restrict__ C,
                                                  int M, int N, int K) {
    __shared__ alignas(16) char lds[32768];
    char* As_hi = lds;
    char* As_lo = lds + 8192;
    char* Bs_hi = lds + 16384;
    char* Bs_lo = lds + 24576;

    const int tid = threadIdx.x, l = tid & 63, w = tid >> 6;
    const int m0 = blockIdx.y * 128, n0 = blockIdx.x * 128;
    const int wr = (w >> 1) * 64, wc = (w & 1) * 64;
    const int q16 = l & 15, g8 = l >> 4;
    const int srow = w * 16 + (l >> 2);

    f32x4 acc[4][4];
#pragma unroll
    for (int i = 0; i < 4; ++i)
#pragma unroll
        for (int j = 0; j < 4; ++j) acc[i][j] = (f32x4){0.f, 0.f, 0.f, 0.f};

    for (int k0 = 0; k0 < K; k0 += 32) {
#pragma unroll
        for (int rd = 0; rd < 2; ++rd) {
            int row = srow + rd * 64;
            int g = (l & 3) ^ (row & 3);
            size_t goffA = (size_t)(m0 + row) * K + k0 + g * 8;
            size_t goffB = (size_t)(n0 + row) * K + k0 + g * 8;
            int lbase = rd * 4096 + w * 1024;
            __builtin_amdgcn_global_load_lds((g_char*)(Ahi + goffA), (lds_char*)(As_hi + lbase), 16, 0, 0);
            __builtin_amdgcn_global_load_lds((g_char*)(Alo + goffA), (lds_char*)(As_lo + lbase), 16, 0, 0);
            __builtin_amdgcn_global_load_lds((g_char*)(Bhi + goffB), (lds_char*)(Bs_hi + lbase), 16, 0, 0);
            __builtin_amdgcn_global_load_lds((g_char*)(Blo + goffB), (lds_char*)(Bs_lo + lbase), 16, 0, 0);
        }
        __syncthreads();

        bf16x8 ah[4], al[4], bh[4], bl[4];
#pragma unroll
        for (int i = 0; i < 4; ++i) {
            int ra = wr + 16 * i + q16, rb = wc + 16 * i + q16;
            ah[i] = *(const bf16x8*)(As_hi + ra * 64 + ((g8 ^ (ra & 3)) * 16));
            al[i] = *(const bf16x8*)(As_lo + ra * 64 + ((g8 ^ (ra & 3)) * 16));
            bh[i] = *(const bf16x8*)(Bs_hi + rb * 64 + ((g8 ^ (rb & 3)) * 16));
            bl[i] = *(const bf16x8*)(Bs_lo + rb * 64 + ((g8 ^ (rb & 3)) * 16));
        }
#pragma unroll
        for (int i = 0; i < 4; ++i)
#pragma unroll
            for (int j = 0; j < 4; ++j) {
                acc[i][j] = __builtin_amdgcn_mfma_f32_16x16x32_bf16(ah[i], bh[j], acc[i][j], 0, 0, 0);
                acc[i][j] = __builtin_amdgcn_mfma_f32_16x16x32_bf16(ah[i], bl[j], acc[i][j], 0, 0, 0);
                acc[i][j] = __builtin_amdgcn_mfma_f32_16x16x32_bf16(al[i], bh[j], acc[i][j], 0, 0, 0);
            }
        __syncthreads();
    }

#pragma unroll
    for (int i = 0; i < 4; ++i)
#pragma unroll
        for (int j = 0; j < 4; ++j) {
            int col = n0 + wc + 16 * j + q16;
            float badd = BIAS ? bias[col] : 0.f;
#pragma unroll
            for (int r = 0; r < 4; ++r) {
                int row = m0 + wr + 16 * i + 4 * g8 + r;
                C[(size_t)row * N + col] = acc[i][j][r] + badd;
            }
        }
}

// ---------------------------------------------------------------------------
// prep_attn: RoPE + bf16 convert + per-head re-layout, one pass over qkvF.
//   qb[bh][t][64]  bf16, RoPE'd, scaled by QSCALE
//   kb[bh][t][64]  bf16, RoPE'd
//   vt[bh][d][2048] bf16, transposed
__global__ __launch_bounds__(256) void prep_attn(const float* __restrict__ qkv,
                                                 const float* __restrict__ cosT,
                                                 const float* __restrict__ sinT,
                                                 unsigned short* __restrict__ qb,
                                                 unsigned short* __restrict__ kb,
                                                 unsigned short* __restrict__ vt) {
    __shared__ float vlds[64][65];
    const int tid = threadIdx.x;
    const int t0 = blockIdx.x * 64;
    const int bh = blockIdx.y;
    const int b = bh >> 4, h = bh & 15;

    if (tid < 128) {
        int sel = tid >> 6;              // 0=q, 1=k
        int t = t0 + (tid & 63);
        const float* p = qkv + ((size_t)(b * T_ + t)) * 3072 + sel * 1024 + h * 64;
        float v[64];
#pragma unroll
        for (int d = 0; d < 64; d += 4) {
            float4 f = *reinterpret_cast<const float4*>(p + d);
            v[d] = f.x; v[d + 1] = f.y; v[d + 2] = f.z; v[d + 3] = f.w;
        }
        const float* c = cosT + t * 32;
        const float* s = sinT + t * 32;
        float o[64];
#pragma unroll
        for (int i = 0; i < 32; ++i) {
            float ci = c[i], si = s[i];
            o[i]      = v[i]      * ci - v[2 * i + 1] * si;
            o[i + 32] = v[i + 32] * ci + v[2 * i]     * si;
        }
        float sc = sel ? 1.0f : QSCALE;
        unsigned short* dst = (sel ? kb : qb) + ((size_t)bh * T_ + t) * 64;
#pragma unroll
        for (int d2 = 0; d2 < 8; ++d2) {
            uint4 u;
            u.x = pack2bf(o[8 * d2 + 0] * sc, o[8 * d2 + 1] * sc);
            u.y = pack2bf(o[8 * d2 + 2] * sc, o[8 * d2 + 3] * sc);
            u.z = pack2bf(o[8 * d2 + 4] * sc, o[8 * d2 + 5] * sc);
            u.w = pack2bf(o[8 * d2 + 6] * sc, o[8 * d2 + 7] * sc);
            *reinterpret_cast<uint4*>(dst + d2 * 8) = u;
        }
    } else {
        int tt = tid - 128;              // 0..127
        int row = tt >> 1, half = tt & 1;
        const float* p = qkv + ((size_t)(b * T_ + t0 + row)) * 3072 + 2048 + h * 64 + half * 32;
#pragma unroll
        for (int j = 0; j < 8; ++j) {
            float4 f = *reinterpret_cast<const float4*>(p + j * 4);
            vlds[row][half * 32 + j * 4 + 0] = f.x;
            vlds[row][half * 32 + j * 4 + 1] = f.y;
            vlds[row][half * 32 + j * 4 + 2] = f.z;
            vlds[row][half * 32 + j * 4 + 3] = f.w;
        }
    }
    __syncthreads();
    if (tid >= 128) {
        int tt = tid - 128;
        int d = tt >> 1, half = tt & 1;
        unsigned out[16];
#pragma unroll
        for (int j = 0; j < 16; ++j)
            out[j] = pack2bf(vlds[half * 32 + 2 * j][d], vlds[half * 32 + 2 * j + 1][d]);
        unsigned short* dst = vt + ((size_t)bh * 64 + d) * T_ + t0 + half * 32;
#pragma unroll
        for (int j = 0; j < 4; ++j)
            *reinterpret_cast<uint4*>(dst + j * 8) =
                make_uint4(out[4 * j], out[4 * j + 1], out[4 * j + 2], out[4 * j + 3]);
    }
}

// ---------------------------------------------------------------------------
// swizzled 16B fragment read: row-major [64][64] bf16 LDS, granule XOR row&7
static __device__ inline bf16x8 frag_read(const char* lds, int row, int elem0) {
    int byte = row * 128 + ((elem0 * 2) ^ ((row & 7) << 4));
    return *reinterpret_cast<const bf16x8*>(lds + byte);
}

// stage one contiguous 8KB tile (64 rows x 128B) into swizzled LDS via
// global_load_lds: linear LDS dest, inverse-swizzled global source (rule #21).
static __device__ inline void stage_contig(const unsigned short* gtile, char* ldst,
                                           int w, int lane) {
#pragma unroll
    for (int n = 0; n < 2; ++n) {
        int loff = n * 4096 + w * 1024;          // wave-uniform LDS base
        int row = (loff >> 7) + (lane >> 3);
        int g = (lane & 7) ^ (row & 7);
        const unsigned short* src = gtile + row * 64 + g * 8;
        __builtin_amdgcn_global_load_lds((g_char*)src, (lds_char*)(ldst + loff), 16, 0, 0);
    }
}

// stage V^T tile: rows d (stride 2048 bf16), cols kt*64..+63
static __device__ inline void stage_vt_tile(const unsigned short* vhead, int kt,
                                            char* ldst, int w, int lane) {
#pragma unroll
    for (int n = 0; n < 2; ++n) {
        int loff = n * 4096 + w * 1024;
        int row = (loff >> 7) + (lane >> 3);     // d
        int g = (lane & 7) ^ (row & 7);
        const unsigned short* src = vhead + (size_t)row * T_ + kt * 64 + g * 8;
        __builtin_amdgcn_global_load_lds((g_char*)src, (lds_char*)(ldst + loff), 16, 0, 0);
    }
}

// ---------------------------------------------------------------------------
// Flash attention v2: bf16 inputs, global_load_lds double-buffered staging,
// exp2-domain softmax with defer-max, setprio'd MFMA clusters.
// Writes ctx directly as split hi/lo bf16 planes.
// LDS map: [0,8K) q | [8K,16K) k buf0 | [16K,24K) k buf1
//          [24K,32K) v buf0 | [32K,40K) v buf1   (no pointer arrays: rule #20 kin)
__global__ __launch_bounds__(256) void attn_mfma(const unsigned short* __restrict__ qb,
                                                 const unsigned short* __restrict__ kb,
                                                 const unsigned short* __restrict__ vt,
                                                 unsigned short* __restrict__ ctx_hi,
                                                 unsigned short* __restrict__ ctx_lo) {
    __shared__ alignas(16) char lds[40960];

    const int tid  = threadIdx.x;
    const int w    = tid >> 6;
    const int lane = tid & 63;
    const int g    = lane >> 4;
    const int q    = lane & 15;

    const int qbk = blockIdx.x;          // q tile 0..31
    const int bh  = blockIdx.y;          // b*16+h
    const int b   = bh >> 4, h = bh & 15;

    const unsigned short* qtile = qb + ((size_t)bh * T_ + qbk * 64) * 64;
    const unsigned short* khead = kb + (size_t)bh * T_ * 64;
    const unsigned short* vhead = vt + (size_t)bh * 64 * T_;

    stage_contig(qtile, lds, w, lane);
    stage_contig(khead, lds + 8192, w, lane);
    stage_vt_tile(vhead, 0, lds + 24576, w, lane);
    __syncthreads();

    const int qrow = 16 * w + q;
    bf16x8 bq0 = frag_read(lds, qrow, 8 * g);
    bf16x8 bq1 = frag_read(lds, qrow, 32 + 8 * g);

    f32x4 acc[4];
#pragma unroll
    for (int i = 0; i < 4; ++i) acc[i] = (f32x4){0.f, 0.f, 0.f, 0.f};
    float mrun = -INFINITY, lrun = 0.f;

    const int srcA = q + 32 * (g & 1);
    const int srcB = srcA + 16;
    const bool hiSel = (g >> 1) != 0;

    for (int kt = 0; kt < 32; ++kt) {
        const int cur = kt & 1;
        if (kt < 31) {                    // T3 2-phase: issue next-tile loads now
            stage_contig(khead + (size_t)(kt + 1) * 64 * 64, lds + 8192 + (cur ^ 1) * 8192, w, lane);
            stage_vt_tile(vhead, kt + 1, lds + 24576 + (cur ^ 1) * 8192, w, lane);
        }
        const char* kc = lds + 8192 + cur * 8192;
        const char* vc = lds + 24576 + cur * 8192;

        // ---- S^T = K . Q^T (scores already in log2 domain via QSCALE)
        f32x4 st[4];
        __builtin_amdgcn_s_setprio(1);
#pragma unroll
        for (int mt = 0; mt < 4; ++mt) {
            int kvrow = 16 * mt + q;
            f32x4 c = (f32x4){0.f, 0.f, 0.f, 0.f};
            c = __builtin_amdgcn_mfma_f32_16x16x32_bf16(frag_read(kc, kvrow, 8 * g), bq0, c, 0, 0, 0);
            c = __builtin_amdgcn_mfma_f32_16x16x32_bf16(frag_read(kc, kvrow, 32 + 8 * g), bq1, c, 0, 0, 0);
            st[mt] = c;
        }
        __builtin_amdgcn_s_setprio(0);

        // ---- online softmax, exp2 domain, defer-max (T13)
        float tmax = st[0][0];
#pragma unroll
        for (int mt = 0; mt < 4; ++mt)
#pragma unroll
            for (int r = 0; r < 4; ++r) tmax = fmaxf(tmax, st[mt][r]);
        tmax = fmaxf(tmax, __shfl_xor(tmax, 16));
        tmax = fmaxf(tmax, __shfl_xor(tmax, 32));
        if (!__all(tmax - mrun <= DEFER_THR)) {
            float mnew = fmaxf(mrun, tmax);
            float corr = exp2f(mrun - mnew);
            lrun *= corr;
#pragma unroll
            for (int i = 0; i < 4; ++i) {
                acc[i][0] *= corr; acc[i][1] *= corr;
                acc[i][2] *= corr; acc[i][3] *= corr;
            }
            mrun = mnew;
        }
        float p[16];
        float tsum = 0.f;
#pragma unroll
        for (int mt = 0; mt < 4; ++mt)
#pragma unroll
            for (int r = 0; r < 4; ++r) {
                float e = exp2f(st[mt][r] - mrun);
                p[4 * mt + r] = e;
                tsum += e;
            }
        tsum += __shfl_xor(tsum, 16);
        tsum += __shfl_xor(tsum, 32);
        lrun += tsum;

        // ---- P^T -> PV B-fragments via register shuffle
        unsigned pk0[4], pk1[4];
#pragma unroll
        for (int mt = 0; mt < 4; ++mt) {
            pk0[mt] = pack2bf(p[4 * mt + 0], p[4 * mt + 1]);
            pk1[mt] = pack2bf(p[4 * mt + 2], p[4 * mt + 3]);
        }
        union { bf16x8 v; unsigned u[4]; } bp0, bp1;
        {
            unsigned xa0 = __shfl(pk0[0], srcA), ya0 = __shfl(pk0[1], srcA);
            unsigned xa1 = __shfl(pk1[0], srcA), ya1 = __shfl(pk1[1], srcA);
            unsigned xb0 = __shfl(pk0[0], srcB), yb0 = __shfl(pk0[1], srcB);
            unsigned xb1 = __shfl(pk1[0], srcB), yb1 = __shfl(pk1[1], srcB);
            bp0.u[0] = hiSel ? ya0 : xa0;
            bp0.u[1] = hiSel ? ya1 : xa1;
            bp0.u[2] = hiSel ? yb0 : xb0;
            bp0.u[3] = hiSel ? yb1 : xb1;
        }
        {
            unsigned xa0 = __shfl(pk0[2], srcA), ya0 = __shfl(pk0[3], srcA);
            unsigned xa1 = __shfl(pk1[2], srcA), ya1 = __shfl(pk1[3], srcA);
            unsigned xb0 = __shfl(pk0[2], srcB), yb0 = __shfl(pk0[3], srcB);
            unsigned xb1 = __shfl(pk1[2], srcB), yb1 = __shfl(pk1[3], srcB);
            bp1.u[0] = hiSel ? ya0 : xa0;
            bp1.u[1] = hiSel ? ya1 : xa1;
            bp1.u[2] = hiSel ? yb0 : xb0;
            bp1.u[3] = hiSel ? yb1 : xb1;
        }

        // ---- O^T += V^T . P^T
        __builtin_amdgcn_s_setprio(1);
#pragma unroll
        for (int nt = 0; nt < 4; ++nt) {
            int nrow = 16 * nt + q;
            acc[nt] = __builtin_amdgcn_mfma_f32_16x16x32_bf16(frag_read(vc, nrow, 8 * g), bp0.v, acc[nt], 0, 0, 0);
            acc[nt] = __builtin_amdgcn_mfma_f32_16x16x32_bf16(frag_read(vc, nrow, 32 + 8 * g), bp1.v, acc[nt], 0, 0, 0);
        }
        __builtin_amdgcn_s_setprio(0);

        __syncthreads();   // drains staging vmcnt + LDS reads; buffers swap
    }

    // ---- epilogue: write ctx as split bf16 planes (hi/lo)
    float inv_l = 1.0f / lrun;
    const int q_abs = qbk * 64 + 16 * w + q;
    size_t obase = ((size_t)b * T_ + q_abs) * 1024 + h * 64;
#pragma unroll
    for (int nt = 0; nt < 4; ++nt)
#pragma unroll
        for (int r = 0; r < 4; ++r) {
            float o = acc[nt][r] * inv_l;
            unsigned short hh = bf16_rne(o);
            union { unsigned u; float f; } hf; hf.u = (unsigned)hh << 16;
            unsigned short ll = bf16_rne(o - hf.f);
            ctx_hi[obase + 16 * nt + 4 * g + r] = hh;
            ctx_lo[obase + 16 * nt + 4 * g + r] = ll;
        }
}

// ---------------------------------------------------------------------------
extern "C" void kernel_launch(void* const* d_in, const int* in_sizes, int n_in,
                              void* d_out, int out_size, void* d_ws, size_t ws_size,
                              hipStream_t stream) {
    const float* x     = (const float*)d_in[0];   // [2,2048,1024]
    const float* w_qkv = (const float*)d_in[1];   // [3072,1024]
    const float* w_out = (const float*)d_in[2];   // [1024,1024]
    const float* b_out = (const float*)d_in[3];   // [1024]
    float* out = (float*)d_out;

    char* base = (char*)d_ws;
    // Phase A (qkv gemm): qkvF @0 (50.3MB); x planes @50.3/58.7MB; wq planes @67.1/73.4MB
    float* qkvF = (float*)base;
    unsigned short* x_hi = (unsigned short*)(base + 50331648);
    unsigned short* x_lo = (unsigned short*)(base + 58720256);
    unsigned short* wq_hi = (unsigned short*)(base + 67108864);
    unsigned short* wq_lo = (unsigned short*)(base + 73400320);
    // Phase B (prep/attn): qb/kb/vt reuse phase-A plane regions (dead after gemm0)
    unsigned short* qb16 = (unsigned short*)(base + 50331648);   // 8MB
    unsigned short* kb16 = (unsigned short*)(base + 58720256);   // 8MB
    unsigned short* vt16 = (unsigned short*)(base + 67108864);   // 8MB
    // Phase C (out gemm): ctx planes + wout planes reuse qkvF region (dead after prep)
    unsigned short* ctx_hi  = (unsigned short*)(base + 0);
    unsigned short* ctx_lo  = (unsigned short*)(base + 8388608);
    unsigned short* wout_hi = (unsigned short*)(base + 16777216);
    unsigned short* wout_lo = (unsigned short*)(base + 18874368);
    // tables
    float* cosT = (float*)(base + 79691776);
    float* sinT = cosT + 65536;

    rope_tables<<<256, 256, 0, stream>>>(cosT, sinT);
    split_kernel<<<2048, 256, 0, stream>>>(x, x_hi, x_lo, 524288);
    split_kernel<<<1536, 256, 0, stream>>>(w_qkv, wq_hi, wq_lo, 393216);
    gemm_split<0><<<dim3(24, 32), 256, 0, stream>>>(x_hi, x_lo, wq_hi, wq_lo,
                                                    nullptr, qkvF, 4096, 3072, 1024);
    prep_attn<<<dim3(32, 32), 256, 0, stream>>>(qkvF, cosT, sinT, qb16, kb16, vt16);
    split_kernel<<<512, 256, 0, stream>>>(w_out, wout_hi, wout_lo, 131072);
    attn_mfma<<<dim3(32, 32), 256, 0, stream>>>(qb16, kb16, vt16, ctx_hi, ctx_lo);
    gemm_split<1><<<dim3(8, 32), 256, 0, stream>>>(ctx_hi, ctx_lo, wout_hi, wout_lo,
                                                   b_out, out, 4096, 1024, 1024);
}

// Round 8
// 308.706 us; speedup vs baseline: 25.5781x; 1.0520x over previous
//
#include <hip/hip_runtime.h>
#include <math.h>

#define B_ 2
#define T_ 2048
#define D_ 1024
#define H_ 16

typedef __attribute__((ext_vector_type(8))) short bf16x8;
typedef __attribute__((ext_vector_type(4))) float f32x4;
typedef __attribute__((address_space(3))) char lds_char;
typedef __attribute__((address_space(1))) const char g_char;

// 0.125 * log2(e): folds the 1/sqrt(64) score scale + exp->exp2 rebase into Q.
#define QSCALE 0.18033688011112042f
#define DEFER_THR 11.5f   // 8 nats in log2 units (T13)

// ---------------------------------------------------------------------------
static __device__ inline unsigned short bf16_rne(float f) {
    union { float f; unsigned u; } v; v.f = f;
    unsigned r = v.u + 0x7FFFu + ((v.u >> 16) & 1u);
    return (unsigned short)(r >> 16);
}
static __device__ inline unsigned pack2bf(float lo, float hi) {
    return (unsigned)bf16_rne(lo) | ((unsigned)bf16_rne(hi) << 16);
}
// hardware exp2 (v_exp_f32 IS 2^x) — avoids OCML wrapper sequence
static __device__ inline float exp2_hw(float x) {
    float r; asm("v_exp_f32 %0, %1" : "=v"(r) : "v"(x)); return r;
}
// packed f32x2 -> bf16x2 RNE in one instruction (T12 primitive)
static __device__ inline unsigned cvt_pk_bf16(float lo, float hi) {
    unsigned r; asm("v_cvt_pk_bf16_f32 %0, %1, %2" : "=v"(r) : "v"(lo), "v"(hi)); return r;
}

// ---------------------------------------------------------------------------
// Split fp32 -> (hi, lo) bf16 planes.  hi = rne(f); lo = rne(f - hi).
__global__ __launch_bounds__(256) void split_kernel(const float* __restrict__ in,
                                                    unsigned short* __restrict__ hi,
                                                    unsigned short* __restrict__ lo,
                                                    int n8) {
    int i = blockIdx.x * 256 + threadIdx.x;
    if (i >= n8) return;
    const float4* ip = (const float4*)in + (size_t)i * 2;
    float4 f0 = ip[0], f1 = ip[1];
    float fs[8] = {f0.x, f0.y, f0.z, f0.w, f1.x, f1.y, f1.z, f1.w};
    unsigned hu[4], lu[4];
#pragma unroll
    for (int j = 0; j < 4; ++j) {
        unsigned short h0 = bf16_rne(fs[2 * j]), h1 = bf16_rne(fs[2 * j + 1]);
        union { unsigned u; float f; } c0, c1;
        c0.u = (unsigned)h0 << 16; c1.u = (unsigned)h1 << 16;
        unsigned short l0 = bf16_rne(fs[2 * j] - c0.f);
        unsigned short l1 = bf16_rne(fs[2 * j + 1] - c1.f);
        hu[j] = (unsigned)h0 | ((unsigned)h1 << 16);
        lu[j] = (unsigned)l0 | ((unsigned)l1 << 16);
    }
    *(uint4*)(hi + (size_t)i * 8) = make_uint4(hu[0], hu[1], hu[2], hu[3]);
    *(uint4*)(lo + (size_t)i * 8) = make_uint4(lu[0], lu[1], lu[2], lu[3]);
}

// ---------------------------------------------------------------------------
// RoPE tables (unchanged)
__global__ __launch_bounds__(256) void rope_tables(float* __restrict__ cosT,
                                                   float* __restrict__ sinT) {
    int idx = blockIdx.x * 256 + threadIdx.x;
    int t = idx >> 5, i = idx & 31;
    double invf_d = exp(-((double)(2 * i) / 64.0) * 9.210340371976184);
    float invf = (float)invf_d;
    float ang = (float)t * invf;
    cosT[idx] = (float)cos((double)ang);
    sinT[idx] = (float)sin((double)ang);
}

// ---------------------------------------------------------------------------
// Split-bf16 GEMM, 128x128 tile + T1 XCD-bijective block swizzle (nwg%8==0).
template <int BIAS>
__global__ __launch_bounds__(256) void gemm_split(const unsigned short* __restrict__ Ahi,
                                                  const unsigned short* __restrict__ Alo,
                                                  const unsigned short* __restrict__ Bhi,
                                                  const unsigned short* __restrict__ Blo,
                                                  const float* __restrict__ bias,
                                                  float* __restrict__ C,
                                                  int M, int N, int K) {
    __shared__ alignas(16) char lds[32768];
    char* As_hi = lds;
    char* As_lo = lds + 8192;
    char* Bs_hi = lds + 16384;
    char* Bs_lo = lds + 24576;

    const int tid = threadIdx.x, l = tid & 63, w = tid >> 6;
    // T1: launched-id -> XCD-contiguous work chunk (bijective; nwg % 8 == 0)
    const int nx = gridDim.x;
    const int bid = blockIdx.y * nx + blockIdx.x;
    const int cpx = (nx * gridDim.y) >> 3;
    const int swz = (bid & 7) * cpx + (bid >> 3);
    const int m0 = (swz / nx) * 128, n0 = (swz % nx) * 128;

    const int wr = (w >> 1) * 64, wc = (w & 1) * 64;
    const int q16 = l & 15, g8 = l >> 4;
    const int srow = w * 16 + (l >> 2);

    f32x4 acc[4][4];
#pragma unroll
    for (int i = 0; i < 4; ++i)
#pragma unroll
        for (int j = 0; j < 4; ++j) acc[i][j] = (f32x4){0.f, 0.f, 0.f, 0.f};

    for (int k0 = 0; k0 < K; k0 += 32) {
#pragma unroll
        for (int rd = 0; rd < 2; ++rd) {
            int row = srow + rd * 64;
            int g = (l & 3) ^ (row & 3);
            size_t goffA = (size_t)(m0 + row) * K + k0 + g * 8;
            size_t goffB = (size_t)(n0 + row) * K + k0 + g * 8;
            int lbase = rd * 4096 + w * 1024;
            __builtin_amdgcn_global_load_lds((g_char*)(Ahi + goffA), (lds_char*)(As_hi + lbase), 16, 0, 0);
            __builtin_amdgcn_global_load_lds((g_char*)(Alo + goffA), (lds_char*)(As_lo + lbase), 16, 0, 0);
            __builtin_amdgcn_global_load_lds((g_char*)(Bhi + goffB), (lds_char*)(Bs_hi + lbase), 16, 0, 0);
            __builtin_amdgcn_global_load_lds((g_char*)(Blo + goffB), (lds_char*)(Bs_lo + lbase), 16, 0, 0);
        }
        __syncthreads();

        bf16x8 ah[4], al[4], bh[4], bl[4];
#pragma unroll
        for (int i = 0; i < 4; ++i) {
            int ra = wr + 16 * i + q16, rb = wc + 16 * i + q16;
            ah[i] = *(const bf16x8*)(As_hi + ra * 64 + ((g8 ^ (ra & 3)) * 16));
            al[i] = *(const bf16x8*)(As_lo + ra * 64 + ((g8 ^ (ra & 3)) * 16));
            bh[i] = *(const bf16x8*)(Bs_hi + rb * 64 + ((g8 ^ (rb & 3)) * 16));
            bl[i] = *(const bf16x8*)(Bs_lo + rb * 64 + ((g8 ^ (rb & 3)) * 16));
        }
#pragma unroll
        for (int i = 0; i < 4; ++i)
#pragma unroll
            for (int j = 0; j < 4; ++j) {
                acc[i][j] = __builtin_amdgcn_mfma_f32_16x16x32_bf16(ah[i], bh[j], acc[i][j], 0, 0, 0);
                acc[i][j] = __builtin_amdgcn_mfma_f32_16x16x32_bf16(ah[i], bl[j], acc[i][j], 0, 0, 0);
                acc[i][j] = __builtin_amdgcn_mfma_f32_16x16x32_bf16(al[i], bh[j], acc[i][j], 0, 0, 0);
            }
        __syncthreads();
    }

#pragma unroll
    for (int i = 0; i < 4; ++i)
#pragma unroll
        for (int j = 0; j < 4; ++j) {
            int col = n0 + wc + 16 * j + q16;
            float badd = BIAS ? bias[col] : 0.f;
#pragma unroll
            for (int r = 0; r < 4; ++r) {
                int row = m0 + wr + 16 * i + 4 * g8 + r;
                C[(size_t)row * N + col] = acc[i][j][r] + badd;
            }
        }
}

// ---------------------------------------------------------------------------
// prep_attn: RoPE + bf16 convert + per-head re-layout (unchanged)
__global__ __launch_bounds__(256) void prep_attn(const float* __restrict__ qkv,
                                                 const float* __restrict__ cosT,
                                                 const float* __restrict__ sinT,
                                                 unsigned short* __restrict__ qb,
                                                 unsigned short* __restrict__ kb,
                                                 unsigned short* __restrict__ vt) {
    __shared__ float vlds[64][65];
    const int tid = threadIdx.x;
    const int t0 = blockIdx.x * 64;
    const int bh = blockIdx.y;
    const int b = bh >> 4, h = bh & 15;

    if (tid < 128) {
        int sel = tid >> 6;              // 0=q, 1=k
        int t = t0 + (tid & 63);
        const float* p = qkv + ((size_t)(b * T_ + t)) * 3072 + sel * 1024 + h * 64;
        float v[64];
#pragma unroll
        for (int d = 0; d < 64; d += 4) {
            float4 f = *reinterpret_cast<const float4*>(p + d);
            v[d] = f.x; v[d + 1] = f.y; v[d + 2] = f.z; v[d + 3] = f.w;
        }
        const float* c = cosT + t * 32;
        const float* s = sinT + t * 32;
        float o[64];
#pragma unroll
        for (int i = 0; i < 32; ++i) {
            float ci = c[i], si = s[i];
            o[i]      = v[i]      * ci - v[2 * i + 1] * si;
            o[i + 32] = v[i + 32] * ci + v[2 * i]     * si;
        }
        float sc = sel ? 1.0f : QSCALE;
        unsigned short* dst = (sel ? kb : qb) + ((size_t)bh * T_ + t) * 64;
#pragma unroll
        for (int d2 = 0; d2 < 8; ++d2) {
            uint4 u;
            u.x = pack2bf(o[8 * d2 + 0] * sc, o[8 * d2 + 1] * sc);
            u.y = pack2bf(o[8 * d2 + 2] * sc, o[8 * d2 + 3] * sc);
            u.z = pack2bf(o[8 * d2 + 4] * sc, o[8 * d2 + 5] * sc);
            u.w = pack2bf(o[8 * d2 + 6] * sc, o[8 * d2 + 7] * sc);
            *reinterpret_cast<uint4*>(dst + d2 * 8) = u;
        }
    } else {
        int tt = tid - 128;              // 0..127
        int row = tt >> 1, half = tt & 1;
        const float* p = qkv + ((size_t)(b * T_ + t0 + row)) * 3072 + 2048 + h * 64 + half * 32;
#pragma unroll
        for (int j = 0; j < 8; ++j) {
            float4 f = *reinterpret_cast<const float4*>(p + j * 4);
            vlds[row][half * 32 + j * 4 + 0] = f.x;
            vlds[row][half * 32 + j * 4 + 1] = f.y;
            vlds[row][half * 32 + j * 4 + 2] = f.z;
            vlds[row][half * 32 + j * 4 + 3] = f.w;
        }
    }
    __syncthreads();
    if (tid >= 128) {
        int tt = tid - 128;
        int d = tt >> 1, half = tt & 1;
        unsigned out[16];
#pragma unroll
        for (int j = 0; j < 16; ++j)
            out[j] = pack2bf(vlds[half * 32 + 2 * j][d], vlds[half * 32 + 2 * j + 1][d]);
        unsigned short* dst = vt + ((size_t)bh * 64 + d) * T_ + t0 + half * 32;
#pragma unroll
        for (int j = 0; j < 4; ++j)
            *reinterpret_cast<uint4*>(dst + j * 8) =
                make_uint4(out[4 * j], out[4 * j + 1], out[4 * j + 2], out[4 * j + 3]);
    }
}

// ---------------------------------------------------------------------------
// swizzled 16B fragment read: row-major [64][64] bf16 LDS, granule XOR row&7
static __device__ inline bf16x8 frag_read(const char* lds, int row, int elem0) {
    int byte = row * 128 + ((elem0 * 2) ^ ((row & 7) << 4));
    return *reinterpret_cast<const bf16x8*>(lds + byte);
}

// stage one contiguous 8KB tile (64 rows x 128B) into swizzled LDS via
// global_load_lds: linear LDS dest, inverse-swizzled global source (rule #21).
static __device__ inline void stage_contig(const unsigned short* gtile, char* ldst,
                                           int w, int lane) {
#pragma unroll
    for (int n = 0; n < 2; ++n) {
        int loff = n * 4096 + w * 1024;          // wave-uniform LDS base
        int row = (loff >> 7) + (lane >> 3);
        int g = (lane & 7) ^ (row & 7);
        const unsigned short* src = gtile + row * 64 + g * 8;
        __builtin_amdgcn_global_load_lds((g_char*)src, (lds_char*)(ldst + loff), 16, 0, 0);
    }
}

// stage V^T tile: rows d (stride 2048 bf16), cols kt*64..+63
static __device__ inline void stage_vt_tile(const unsigned short* vhead, int kt,
                                            char* ldst, int w, int lane) {
#pragma unroll
    for (int n = 0; n < 2; ++n) {
        int loff = n * 4096 + w * 1024;
        int row = (loff >> 7) + (lane >> 3);     // d
        int g = (lane & 7) ^ (row & 7);
        const unsigned short* src = vhead + (size_t)row * T_ + kt * 64 + g * 8;
        __builtin_amdgcn_global_load_lds((g_char*)src, (lds_char*)(ldst + loff), 16, 0, 0);
    }
}

// ---------------------------------------------------------------------------
// Flash attention v3: asm exp2/cvt_pk, deferred l-merge, XCD swizzle.
// LDS map: [0,8K) q | [8K,16K) k buf0 | [16K,24K) k buf1
//          [24K,32K) v buf0 | [32K,40K) v buf1
__global__ __launch_bounds__(256) void attn_mfma(const unsigned short* __restrict__ qb,
                                                 const unsigned short* __restrict__ kb,
                                                 const unsigned short* __restrict__ vt,
                                                 unsigned short* __restrict__ ctx_hi,
                                                 unsigned short* __restrict__ ctx_lo) {
    __shared__ alignas(16) char lds[40960];

    const int tid  = threadIdx.x;
    const int w    = tid >> 6;
    const int lane = tid & 63;
    const int g    = lane >> 4;
    const int q    = lane & 15;

    // T1 swizzle: nwg = 1024, 128 blocks per XCD chunk = 4 full bh of q-tiles
    const int bid = blockIdx.y * 32 + blockIdx.x;
    const int swz = (bid & 7) * 128 + (bid >> 3);
    const int qbk = swz & 31;            // q tile 0..31
    const int bh  = swz >> 5;            // b*16+h
    const int b   = bh >> 4, h = bh & 15;

    const unsigned short* qtile = qb + ((size_t)bh * T_ + qbk * 64) * 64;
    const unsigned short* khead = kb + (size_t)bh * T_ * 64;
    const unsigned short* vhead = vt + (size_t)bh * 64 * T_;

    stage_contig(qtile, lds, w, lane);
    stage_contig(khead, lds + 8192, w, lane);
    stage_vt_tile(vhead, 0, lds + 24576, w, lane);
    __syncthreads();

    const int qrow = 16 * w + q;
    bf16x8 bq0 = frag_read(lds, qrow, 8 * g);
    bf16x8 bq1 = frag_read(lds, qrow, 32 + 8 * g);

    f32x4 acc[4];
#pragma unroll
    for (int i = 0; i < 4; ++i) acc[i] = (f32x4){0.f, 0.f, 0.f, 0.f};
    float mrun = -INFINITY, lsum = 0.f;  // lsum = per-lane partial row sum

    const int srcA = q + 32 * (g & 1);
    const int srcB = srcA + 16;
    const bool hiSel = (g >> 1) != 0;

    for (int kt = 0; kt < 32; ++kt) {
        const int cur = kt & 1;
        if (kt < 31) {                    // 2-phase: issue next-tile loads now
            stage_contig(khead + (size_t)(kt + 1) * 64 * 64, lds + 8192 + (cur ^ 1) * 8192, w, lane);
            stage_vt_tile(vhead, kt + 1, lds + 24576 + (cur ^ 1) * 8192, w, lane);
        }
        const char* kc = lds + 8192 + cur * 8192;
        const char* vc = lds + 24576 + cur * 8192;

        // ---- S^T = K . Q^T (scores in log2 domain via QSCALE)
        f32x4 st[4];
        __builtin_amdgcn_s_setprio(1);
#pragma unroll
        for (int mt = 0; mt < 4; ++mt) {
            int kvrow = 16 * mt + q;
            f32x4 c = (f32x4){0.f, 0.f, 0.f, 0.f};
            c = __builtin_amdgcn_mfma_f32_16x16x32_bf16(frag_read(kc, kvrow, 8 * g), bq0, c, 0, 0, 0);
            c = __builtin_amdgcn_mfma_f32_16x16x32_bf16(frag_read(kc, kvrow, 32 + 8 * g), bq1, c, 0, 0, 0);
            st[mt] = c;
        }
        __builtin_amdgcn_s_setprio(0);

        // ---- online softmax, exp2 domain, defer-max (T13)
        float tmax = fmaxf(fmaxf(st[0][0], st[0][1]), fmaxf(st[0][2], st[0][3]));
#pragma unroll
        for (int mt = 1; mt < 4; ++mt)
            tmax = fmaxf(tmax, fmaxf(fmaxf(st[mt][0], st[mt][1]),
                                     fmaxf(st[mt][2], st[mt][3])));
        tmax = fmaxf(tmax, __shfl_xor(tmax, 16));
        tmax = fmaxf(tmax, __shfl_xor(tmax, 32));
        if (!__all(tmax - mrun <= DEFER_THR)) {
            float mnew = fmaxf(mrun, tmax);
            float corr = exp2_hw(mrun - mnew);
            lsum *= corr;                 // partial-sum rescale (distributive)
#pragma unroll
            for (int i = 0; i < 4; ++i) {
                acc[i][0] *= corr; acc[i][1] *= corr;
                acc[i][2] *= corr; acc[i][3] *= corr;
            }
            mrun = mnew;
        }
        float p[16];
#pragma unroll
        for (int mt = 0; mt < 4; ++mt)
#pragma unroll
            for (int r = 0; r < 4; ++r) {
                float e = exp2_hw(st[mt][r] - mrun);
                p[4 * mt + r] = e;
                lsum += e;                // merged once, in the epilogue
            }

        // ---- P^T -> PV B-fragments: cvt_pk pairs + register shuffle
        unsigned pk0[4], pk1[4];
#pragma unroll
        for (int mt = 0; mt < 4; ++mt) {
            pk0[mt] = cvt_pk_bf16(p[4 * mt + 0], p[4 * mt + 1]);
            pk1[mt] = cvt_pk_bf16(p[4 * mt + 2], p[4 * mt + 3]);
        }
        union { bf16x8 v; unsigned u[4]; } bp0, bp1;
        {
            unsigned xa0 = __shfl(pk0[0], srcA), ya0 = __shfl(pk0[1], srcA);
            unsigned xa1 = __shfl(pk1[0], srcA), ya1 = __shfl(pk1[1], srcA);
            unsigned xb0 = __shfl(pk0[0], srcB), yb0 = __shfl(pk0[1], srcB);
            unsigned xb1 = __shfl(pk1[0], srcB), yb1 = __shfl(pk1[1], srcB);
            bp0.u[0] = hiSel ? ya0 : xa0;
            bp0.u[1] = hiSel ? ya1 : xa1;
            bp0.u[2] = hiSel ? yb0 : xb0;
            bp0.u[3] = hiSel ? yb1 : xb1;
        }
        {
            unsigned xa0 = __shfl(pk0[2], srcA), ya0 = __shfl(pk0[3], srcA);
            unsigned xa1 = __shfl(pk1[2], srcA), ya1 = __shfl(pk1[3], srcA);
            unsigned xb0 = __shfl(pk0[2], srcB), yb0 = __shfl(pk0[3], srcB);
            unsigned xb1 = __shfl(pk1[2], srcB), yb1 = __shfl(pk1[3], srcB);
            bp1.u[0] = hiSel ? ya0 : xa0;
            bp1.u[1] = hiSel ? ya1 : xa1;
            bp1.u[2] = hiSel ? yb0 : xb0;
            bp1.u[3] = hiSel ? yb1 : xb1;
        }

        // ---- O^T += V^T . P^T
        __builtin_amdgcn_s_setprio(1);
#pragma unroll
        for (int nt = 0; nt < 4; ++nt) {
            int nrow = 16 * nt + q;
            acc[nt] = __builtin_amdgcn_mfma_f32_16x16x32_bf16(frag_read(vc, nrow, 8 * g), bp0.v, acc[nt], 0, 0, 0);
            acc[nt] = __builtin_amdgcn_mfma_f32_16x16x32_bf16(frag_read(vc, nrow, 32 + 8 * g), bp1.v, acc[nt], 0, 0, 0);
        }
        __builtin_amdgcn_s_setprio(0);

        __syncthreads();   // drains staging vmcnt + LDS reads; buffers swap
    }

    // ---- merge the 4 group-partials of the row sum (deferred from the loop)
    lsum += __shfl_xor(lsum, 16);
    lsum += __shfl_xor(lsum, 32);

    // ---- epilogue: write ctx as split bf16 planes (hi/lo)
    float inv_l = 1.0f / lsum;
    const int q_abs = qbk * 64 + 16 * w + q;
    size_t obase = ((size_t)b * T_ + q_abs) * 1024 + h * 64;
#pragma unroll
    for (int nt = 0; nt < 4; ++nt)
#pragma unroll
        for (int r = 0; r < 4; ++r) {
            float o = acc[nt][r] * inv_l;
            unsigned short hh = bf16_rne(o);
            union { unsigned u; float f; } hf; hf.u = (unsigned)hh << 16;
            unsigned short ll = bf16_rne(o - hf.f);
            ctx_hi[obase + 16 * nt + 4 * g + r] = hh;
            ctx_lo[obase + 16 * nt + 4 * g + r] = ll;
        }
}

// ---------------------------------------------------------------------------
extern "C" void kernel_launch(void* const* d_in, const int* in_sizes, int n_in,
                              void* d_out, int out_size, void* d_ws, size_t ws_size,
                              hipStream_t stream) {
    const float* x     = (const float*)d_in[0];   // [2,2048,1024]
    const float* w_qkv = (const float*)d_in[1];   // [3072,1024]
    const float* w_out = (const float*)d_in[2];   // [1024,1024]
    const float* b_out = (const float*)d_in[3];   // [1024]
    float* out = (float*)d_out;

    char* base = (char*)d_ws;
    // Phase A (qkv gemm): qkvF @0 (50.3MB); x planes @50.3/58.7MB; wq planes @67.1/73.4MB
    float* qkvF = (float*)base;
    unsigned short* x_hi = (unsigned short*)(base + 50331648);
    unsigned short* x_lo = (unsigned short*)(base + 58720256);
    unsigned short* wq_hi = (unsigned short*)(base + 67108864);
    unsigned short* wq_lo = (unsigned short*)(base + 73400320);
    // Phase B (prep/attn): qb/kb/vt reuse phase-A plane regions (dead after gemm0)
    unsigned short* qb16 = (unsigned short*)(base + 50331648);   // 8MB
    unsigned short* kb16 = (unsigned short*)(base + 58720256);   // 8MB
    unsigned short* vt16 = (unsigned short*)(base + 67108864);   // 8MB
    // Phase C (out gemm): ctx planes + wout planes reuse qkvF region (dead after prep)
    unsigned short* ctx_hi  = (unsigned short*)(base + 0);
    unsigned short* ctx_lo  = (unsigned short*)(base + 8388608);
    unsigned short* wout_hi = (unsigned short*)(base + 16777216);
    unsigned short* wout_lo = (unsigned short*)(base + 18874368);
    // tables
    float* cosT = (float*)(base + 79691776);
    float* sinT = cosT + 65536;

    rope_tables<<<256, 256, 0, stream>>>(cosT, sinT);
    split_kernel<<<2048, 256, 0, stream>>>(x, x_hi, x_lo, 524288);
    split_kernel<<<1536, 256, 0, stream>>>(w_qkv, wq_hi, wq_lo, 393216);
    gemm_split<0><<<dim3(24, 32), 256, 0, stream>>>(x_hi, x_lo, wq_hi, wq_lo,
                                                    nullptr, qkvF, 4096, 3072, 1024);
    prep_attn<<<dim3(32, 32), 256, 0, stream>>>(qkvF, cosT, sinT, qb16, kb16, vt16);
    split_kernel<<<512, 256, 0, stream>>>(w_out, wout_hi, wout_lo, 131072);
    attn_mfma<<<dim3(32, 32), 256, 0, stream>>>(qb16, kb16, vt16, ctx_hi, ctx_lo);
    gemm_split<1><<<dim3(8, 32), 256, 0, stream>>>(ctx_hi, ctx_lo, wout_hi, wout_lo,
                                                   b_out, out, 4096, 1024, 1024);
}

// Round 9
// 294.695 us; speedup vs baseline: 26.7943x; 1.0475x over previous
//
#include <hip/hip_runtime.h>
#include <math.h>

#define B_ 2
#define T_ 2048
#define D_ 1024
#define H_ 16

typedef __attribute__((ext_vector_type(8))) short bf16x8;
typedef __attribute__((ext_vector_type(4))) float f32x4;
typedef __attribute__((address_space(3))) char lds_char;
typedef __attribute__((address_space(1))) const char g_char;

// 0.125 * log2(e): folds the 1/sqrt(64) score scale + exp->exp2 rebase into Q.
#define QSCALE 0.18033688011112042f
#define DEFER_THR 11.5f   // 8 nats in log2 units (T13)

// ---------------------------------------------------------------------------
static __device__ inline unsigned short bf16_rne(float f) {
    union { float f; unsigned u; } v; v.f = f;
    unsigned r = v.u + 0x7FFFu + ((v.u >> 16) & 1u);
    return (unsigned short)(r >> 16);
}
static __device__ inline unsigned pack2bf(float lo, float hi) {
    return (unsigned)bf16_rne(lo) | ((unsigned)bf16_rne(hi) << 16);
}
// hardware exp2 (v_exp_f32 IS 2^x) — avoids OCML wrapper sequence
static __device__ inline float exp2_hw(float x) {
    float r; asm("v_exp_f32 %0, %1" : "=v"(r) : "v"(x)); return r;
}
// packed f32x2 -> bf16x2 RNE in one instruction (T12 primitive)
static __device__ inline unsigned cvt_pk_bf16(float lo, float hi) {
    unsigned r; asm("v_cvt_pk_bf16_f32 %0, %1, %2" : "=v"(r) : "v"(lo), "v"(hi)); return r;
}

// ---------------------------------------------------------------------------
// split body: 8 fp32 -> (hi, lo) bf16 planes.  hi = rne(f); lo = rne(f - hi).
static __device__ inline void split8(const float* __restrict__ in,
                                     unsigned short* __restrict__ hi,
                                     unsigned short* __restrict__ lo, int i) {
    const float4* ip = (const float4*)in + (size_t)i * 2;
    float4 f0 = ip[0], f1 = ip[1];
    float fs[8] = {f0.x, f0.y, f0.z, f0.w, f1.x, f1.y, f1.z, f1.w};
    unsigned hu[4], lu[4];
#pragma unroll
    for (int j = 0; j < 4; ++j) {
        unsigned short h0 = bf16_rne(fs[2 * j]), h1 = bf16_rne(fs[2 * j + 1]);
        union { unsigned u; float f; } c0, c1;
        c0.u = (unsigned)h0 << 16; c1.u = (unsigned)h1 << 16;
        unsigned short l0 = bf16_rne(fs[2 * j] - c0.f);
        unsigned short l1 = bf16_rne(fs[2 * j + 1] - c1.f);
        hu[j] = (unsigned)h0 | ((unsigned)h1 << 16);
        lu[j] = (unsigned)l0 | ((unsigned)l1 << 16);
    }
    *(uint4*)(hi + (size_t)i * 8) = make_uint4(hu[0], hu[1], hu[2], hu[3]);
    *(uint4*)(lo + (size_t)i * 8) = make_uint4(lu[0], lu[1], lu[2], lu[3]);
}

// split_kernel retained for the w_out split (must run after prep_attn frees
// its aliased region).
__global__ __launch_bounds__(256) void split_kernel(const float* __restrict__ in,
                                                    unsigned short* __restrict__ hi,
                                                    unsigned short* __restrict__ lo,
                                                    int n8) {
    int i = blockIdx.x * 256 + threadIdx.x;
    if (i >= n8) return;
    split8(in, hi, lo, i);
}

// ---------------------------------------------------------------------------
// fused_prep: split(x) [blocks 0..2047], split(w_qkv) [2048..3583],
// rope tables [3584..3839].  One launch instead of three.
__global__ __launch_bounds__(256) void fused_prep(const float* __restrict__ x,
                                                  const float* __restrict__ wq,
                                                  unsigned short* __restrict__ x_hi,
                                                  unsigned short* __restrict__ x_lo,
                                                  unsigned short* __restrict__ wq_hi,
                                                  unsigned short* __restrict__ wq_lo,
                                                  float* __restrict__ cosT,
                                                  float* __restrict__ sinT) {
    const int bid = blockIdx.x, tid = threadIdx.x;
    if (bid < 2048) {
        split8(x, x_hi, x_lo, bid * 256 + tid);
    } else if (bid < 3584) {
        split8(wq, wq_hi, wq_lo, (bid - 2048) * 256 + tid);
    } else {
        int idx = (bid - 3584) * 256 + tid;      // t*32+i, 65536 total
        int t = idx >> 5, i = idx & 31;
        double invf_d = exp(-((double)(2 * i) / 64.0) * 9.210340371976184);
        float invf = (float)invf_d;
        float ang = (float)t * invf;
        cosT[idx] = (float)cos((double)ang);
        sinT[idx] = (float)sin((double)ang);
    }
}

// ---------------------------------------------------------------------------
// Split-bf16 GEMM, 128x128 tile + T1 XCD-bijective block swizzle (nwg%8==0).
template <int BIAS>
__global__ __launch_bounds__(256) void gemm_split(const unsigned short* __restrict__ Ahi,
                                                  const unsigned short* __restrict__ Alo,
                                                  const unsigned short* __restrict__ Bhi,
                                                  const unsigned short* __restrict__ Blo,
                                                  const float* __restrict__ bias,
                                                  float* __restrict__ C,
                                                  int M, int N, int K) {
    __shared__ alignas(16) char lds[32768];
    char* As_hi = lds;
    char* As_lo = lds + 8192;
    char* Bs_hi = lds + 16384;
    char* Bs_lo = lds + 24576;

    const int tid = threadIdx.x, l = tid & 63, w = tid >> 6;
    const int nx = gridDim.x;
    const int bid = blockIdx.y * nx + blockIdx.x;
    const int cpx = (nx * gridDim.y) >> 3;
    const int swz = (bid & 7) * cpx + (bid >> 3);
    const int m0 = (swz / nx) * 128, n0 = (swz % nx) * 128;

    const int wr = (w >> 1) * 64, wc = (w & 1) * 64;
    const int q16 = l & 15, g8 = l >> 4;
    const int srow = w * 16 + (l >> 2);

    f32x4 acc[4][4];
#pragma unroll
    for (int i = 0; i < 4; ++i)
#pragma unroll
        for (int j = 0; j < 4; ++j) acc[i][j] = (f32x4){0.f, 0.f, 0.f, 0.f};

    for (int k0 = 0; k0 < K; k0 += 32) {
#pragma unroll
        for (int rd = 0; rd < 2; ++rd) {
            int row = srow + rd * 64;
            int g = (l & 3) ^ (row & 3);
            size_t goffA = (size_t)(m0 + row) * K + k0 + g * 8;
            size_t goffB = (size_t)(n0 + row) * K + k0 + g * 8;
            int lbase = rd * 4096 + w * 1024;
            __builtin_amdgcn_global_load_lds((g_char*)(Ahi + goffA), (lds_char*)(As_hi + lbase), 16, 0, 0);
            __builtin_amdgcn_global_load_lds((g_char*)(Alo + goffA), (lds_char*)(As_lo + lbase), 16, 0, 0);
            __builtin_amdgcn_global_load_lds((g_char*)(Bhi + goffB), (lds_char*)(Bs_hi + lbase), 16, 0, 0);
            __builtin_amdgcn_global_load_lds((g_char*)(Blo + goffB), (lds_char*)(Bs_lo + lbase), 16, 0, 0);
        }
        __syncthreads();

        bf16x8 ah[4], al[4], bh[4], bl[4];
#pragma unroll
        for (int i = 0; i < 4; ++i) {
            int ra = wr + 16 * i + q16, rb = wc + 16 * i + q16;
            ah[i] = *(const bf16x8*)(As_hi + ra * 64 + ((g8 ^ (ra & 3)) * 16));
            al[i] = *(const bf16x8*)(As_lo + ra * 64 + ((g8 ^ (ra & 3)) * 16));
            bh[i] = *(const bf16x8*)(Bs_hi + rb * 64 + ((g8 ^ (rb & 3)) * 16));
            bl[i] = *(const bf16x8*)(Bs_lo + rb * 64 + ((g8 ^ (rb & 3)) * 16));
        }
#pragma unroll
        for (int i = 0; i < 4; ++i)
#pragma unroll
            for (int j = 0; j < 4; ++j) {
                acc[i][j] = __builtin_amdgcn_mfma_f32_16x16x32_bf16(ah[i], bh[j], acc[i][j], 0, 0, 0);
                acc[i][j] = __builtin_amdgcn_mfma_f32_16x16x32_bf16(ah[i], bl[j], acc[i][j], 0, 0, 0);
                acc[i][j] = __builtin_amdgcn_mfma_f32_16x16x32_bf16(al[i], bh[j], acc[i][j], 0, 0, 0);
            }
        __syncthreads();
    }

#pragma unroll
    for (int i = 0; i < 4; ++i)
#pragma unroll
        for (int j = 0; j < 4; ++j) {
            int col = n0 + wc + 16 * j + q16;
            float badd = BIAS ? bias[col] : 0.f;
#pragma unroll
            for (int r = 0; r < 4; ++r) {
                int row = m0 + wr + 16 * i + 4 * g8 + r;
                C[(size_t)row * N + col] = acc[i][j][r] + badd;
            }
        }
}

// ---------------------------------------------------------------------------
// Split-bf16 GEMM, 128x64 tile — for small-N GEMMs where 128x128 under-fills
// the grid (gemm1: 256 blocks = 1/CU -> barrier drains fully exposed).
// 512 blocks = 2 blocks/CU; co-resident blocks overlap each other's stalls.
template <int BIAS>
__global__ __launch_bounds__(256) void gemm_split_n64(const unsigned short* __restrict__ Ahi,
                                                      const unsigned short* __restrict__ Alo,
                                                      const unsigned short* __restrict__ Bhi,
                                                      const unsigned short* __restrict__ Blo,
                                                      const float* __restrict__ bias,
                                                      float* __restrict__ C,
                                                      int M, int N, int K) {
    __shared__ alignas(16) char lds[24576];      // A hi/lo 8K+8K, B hi/lo 4K+4K
    char* As_hi = lds;
    char* As_lo = lds + 8192;
    char* Bs_hi = lds + 16384;
    char* Bs_lo = lds + 20480;

    const int tid = threadIdx.x, l = tid & 63, w = tid >> 6;
    const int nx = gridDim.x;
    const int bid = blockIdx.y * nx + blockIdx.x;
    const int cpx = (nx * gridDim.y) >> 3;
    const int swz = (bid & 7) * cpx + (bid >> 3);
    const int m0 = (swz / nx) * 128, n0 = (swz % nx) * 64;

    const int wr = (w >> 1) * 64, wc = (w & 1) * 32;   // wave: 64 rows x 32 cols
    const int q16 = l & 15, g8 = l >> 4;
    const int srow = w * 16 + (l >> 2);

    f32x4 acc[4][2];
#pragma unroll
    for (int i = 0; i < 4; ++i)
#pragma unroll
        for (int j = 0; j < 2; ++j) acc[i][j] = (f32x4){0.f, 0.f, 0.f, 0.f};

    for (int k0 = 0; k0 < K; k0 += 32) {
        // A planes: 128 rows, 2 staging rounds
#pragma unroll
        for (int rd = 0; rd < 2; ++rd) {
            int row = srow + rd * 64;
            int g = (l & 3) ^ (row & 3);
            size_t goffA = (size_t)(m0 + row) * K + k0 + g * 8;
            int lbase = rd * 4096 + w * 1024;
            __builtin_amdgcn_global_load_lds((g_char*)(Ahi + goffA), (lds_char*)(As_hi + lbase), 16, 0, 0);
            __builtin_amdgcn_global_load_lds((g_char*)(Alo + goffA), (lds_char*)(As_lo + lbase), 16, 0, 0);
        }
        // B planes: 64 rows, single round
        {
            int row = srow;
            int g = (l & 3) ^ (row & 3);
            size_t goffB = (size_t)(n0 + row) * K + k0 + g * 8;
            int lbase = w * 1024;
            __builtin_amdgcn_global_load_lds((g_char*)(Bhi + goffB), (lds_char*)(Bs_hi + lbase), 16, 0, 0);
            __builtin_amdgcn_global_load_lds((g_char*)(Blo + goffB), (lds_char*)(Bs_lo + lbase), 16, 0, 0);
        }
        __syncthreads();

        bf16x8 ah[4], al[4], bh[2], bl[2];
#pragma unroll
        for (int i = 0; i < 4; ++i) {
            int ra = wr + 16 * i + q16;
            ah[i] = *(const bf16x8*)(As_hi + ra * 64 + ((g8 ^ (ra & 3)) * 16));
            al[i] = *(const bf16x8*)(As_lo + ra * 64 + ((g8 ^ (ra & 3)) * 16));
        }
#pragma unroll
        for (int j = 0; j < 2; ++j) {
            int rb = wc + 16 * j + q16;
            bh[j] = *(const bf16x8*)(Bs_hi + rb * 64 + ((g8 ^ (rb & 3)) * 16));
            bl[j] = *(const bf16x8*)(Bs_lo + rb * 64 + ((g8 ^ (rb & 3)) * 16));
        }
#pragma unroll
        for (int i = 0; i < 4; ++i)
#pragma unroll
            for (int j = 0; j < 2; ++j) {
                acc[i][j] = __builtin_amdgcn_mfma_f32_16x16x32_bf16(ah[i], bh[j], acc[i][j], 0, 0, 0);
                acc[i][j] = __builtin_amdgcn_mfma_f32_16x16x32_bf16(ah[i], bl[j], acc[i][j], 0, 0, 0);
                acc[i][j] = __builtin_amdgcn_mfma_f32_16x16x32_bf16(al[i], bh[j], acc[i][j], 0, 0, 0);
            }
        __syncthreads();
    }

#pragma unroll
    for (int i = 0; i < 4; ++i)
#pragma unroll
        for (int j = 0; j < 2; ++j) {
            int col = n0 + wc + 16 * j + q16;
            float badd = BIAS ? bias[col] : 0.f;
#pragma unroll
            for (int r = 0; r < 4; ++r) {
                int row = m0 + wr + 16 * i + 4 * g8 + r;
                C[(size_t)row * N + col] = acc[i][j][r] + badd;
            }
        }
}

// ---------------------------------------------------------------------------
// prep_attn: RoPE + bf16 convert + per-head re-layout (unchanged)
__global__ __launch_bounds__(256) void prep_attn(const float* __restrict__ qkv,
                                                 const float* __restrict__ cosT,
                                                 const float* __restrict__ sinT,
                                                 unsigned short* __restrict__ qb,
                                                 unsigned short* __restrict__ kb,
                                                 unsigned short* __restrict__ vt) {
    __shared__ float vlds[64][65];
    const int tid = threadIdx.x;
    const int t0 = blockIdx.x * 64;
    const int bh = blockIdx.y;
    const int b = bh >> 4, h = bh & 15;

    if (tid < 128) {
        int sel = tid >> 6;              // 0=q, 1=k
        int t = t0 + (tid & 63);
        const float* p = qkv + ((size_t)(b * T_ + t)) * 3072 + sel * 1024 + h * 64;
        float v[64];
#pragma unroll
        for (int d = 0; d < 64; d += 4) {
            float4 f = *reinterpret_cast<const float4*>(p + d);
            v[d] = f.x; v[d + 1] = f.y; v[d + 2] = f.z; v[d + 3] = f.w;
        }
        const float* c = cosT + t * 32;
        const float* s = sinT + t * 32;
        float o[64];
#pragma unroll
        for (int i = 0; i < 32; ++i) {
            float ci = c[i], si = s[i];
            o[i]      = v[i]      * ci - v[2 * i + 1] * si;
            o[i + 32] = v[i + 32] * ci + v[2 * i]     * si;
        }
        float sc = sel ? 1.0f : QSCALE;
        unsigned short* dst = (sel ? kb : qb) + ((size_t)bh * T_ + t) * 64;
#pragma unroll
        for (int d2 = 0; d2 < 8; ++d2) {
            uint4 u;
            u.x = pack2bf(o[8 * d2 + 0] * sc, o[8 * d2 + 1] * sc);
            u.y = pack2bf(o[8 * d2 + 2] * sc, o[8 * d2 + 3] * sc);
            u.z = pack2bf(o[8 * d2 + 4] * sc, o[8 * d2 + 5] * sc);
            u.w = pack2bf(o[8 * d2 + 6] * sc, o[8 * d2 + 7] * sc);
            *reinterpret_cast<uint4*>(dst + d2 * 8) = u;
        }
    } else {
        int tt = tid - 128;              // 0..127
        int row = tt >> 1, half = tt & 1;
        const float* p = qkv + ((size_t)(b * T_ + t0 + row)) * 3072 + 2048 + h * 64 + half * 32;
#pragma unroll
        for (int j = 0; j < 8; ++j) {
            float4 f = *reinterpret_cast<const float4*>(p + j * 4);
            vlds[row][half * 32 + j * 4 + 0] = f.x;
            vlds[row][half * 32 + j * 4 + 1] = f.y;
            vlds[row][half * 32 + j * 4 + 2] = f.z;
            vlds[row][half * 32 + j * 4 + 3] = f.w;
        }
    }
    __syncthreads();
    if (tid >= 128) {
        int tt = tid - 128;
        int d = tt >> 1, half = tt & 1;
        unsigned out[16];
#pragma unroll
        for (int j = 0; j < 16; ++j)
            out[j] = pack2bf(vlds[half * 32 + 2 * j][d], vlds[half * 32 + 2 * j + 1][d]);
        unsigned short* dst = vt + ((size_t)bh * 64 + d) * T_ + t0 + half * 32;
#pragma unroll
        for (int j = 0; j < 4; ++j)
            *reinterpret_cast<uint4*>(dst + j * 8) =
                make_uint4(out[4 * j], out[4 * j + 1], out[4 * j + 2], out[4 * j + 3]);
    }
}

// ---------------------------------------------------------------------------
// swizzled 16B fragment read: row-major [64][64] bf16 LDS, granule XOR row&7
static __device__ inline bf16x8 frag_read(const char* lds, int row, int elem0) {
    int byte = row * 128 + ((elem0 * 2) ^ ((row & 7) << 4));
    return *reinterpret_cast<const bf16x8*>(lds + byte);
}

// stage one contiguous 8KB tile (64 rows x 128B) into swizzled LDS via
// global_load_lds: linear LDS dest, inverse-swizzled global source (rule #21).
static __device__ inline void stage_contig(const unsigned short* gtile, char* ldst,
                                           int w, int lane) {
#pragma unroll
    for (int n = 0; n < 2; ++n) {
        int loff = n * 4096 + w * 1024;          // wave-uniform LDS base
        int row = (loff >> 7) + (lane >> 3);
        int g = (lane & 7) ^ (row & 7);
        const unsigned short* src = gtile + row * 64 + g * 8;
        __builtin_amdgcn_global_load_lds((g_char*)src, (lds_char*)(ldst + loff), 16, 0, 0);
    }
}

// stage V^T tile: rows d (stride 2048 bf16), cols kt*64..+63
static __device__ inline void stage_vt_tile(const unsigned short* vhead, int kt,
                                            char* ldst, int w, int lane) {
#pragma unroll
    for (int n = 0; n < 2; ++n) {
        int loff = n * 4096 + w * 1024;
        int row = (loff >> 7) + (lane >> 3);     // d
        int g = (lane & 7) ^ (row & 7);
        const unsigned short* src = vhead + (size_t)row * T_ + kt * 64 + g * 8;
        __builtin_amdgcn_global_load_lds((g_char*)src, (lds_char*)(ldst + loff), 16, 0, 0);
    }
}

// ---------------------------------------------------------------------------
// Flash attention v3 (unchanged from round 8 — control this round).
// LDS map: [0,8K) q | [8K,16K) k buf0 | [16K,24K) k buf1
//          [24K,32K) v buf0 | [32K,40K) v buf1
__global__ __launch_bounds__(256) void attn_mfma(const unsigned short* __restrict__ qb,
                                                 const unsigned short* __restrict__ kb,
                                                 const unsigned short* __restrict__ vt,
                                                 unsigned short* __restrict__ ctx_hi,
                                                 unsigned short* __restrict__ ctx_lo) {
    __shared__ alignas(16) char lds[40960];

    const int tid  = threadIdx.x;
    const int w    = tid >> 6;
    const int lane = tid & 63;
    const int g    = lane >> 4;
    const int q    = lane & 15;

    // T1 swizzle: nwg = 1024, 128 blocks per XCD chunk = 4 full bh of q-tiles
    const int bid = blockIdx.y * 32 + blockIdx.x;
    const int swz = (bid & 7) * 128 + (bid >> 3);
    const int qbk = swz & 31;            // q tile 0..31
    const int bh  = swz >> 5;            // b*16+h
    const int b   = bh >> 4, h = bh & 15;

    const unsigned short* qtile = qb + ((size_t)bh * T_ + qbk * 64) * 64;
    const unsigned short* khead = kb + (size_t)bh * T_ * 64;
    const unsigned short* vhead = vt + (size_t)bh * 64 * T_;

    stage_contig(qtile, lds, w, lane);
    stage_contig(khead, lds + 8192, w, lane);
    stage_vt_tile(vhead, 0, lds + 24576, w, lane);
    __syncthreads();

    const int qrow = 16 * w + q;
    bf16x8 bq0 = frag_read(lds, qrow, 8 * g);
    bf16x8 bq1 = frag_read(lds, qrow, 32 + 8 * g);

    f32x4 acc[4];
#pragma unroll
    for (int i = 0; i < 4; ++i) acc[i] = (f32x4){0.f, 0.f, 0.f, 0.f};
    float mrun = -INFINITY, lsum = 0.f;  // lsum = per-lane partial row sum

    const int srcA = q + 32 * (g & 1);
    const int srcB = srcA + 16;
    const bool hiSel = (g >> 1) != 0;

    for (int kt = 0; kt < 32; ++kt) {
        const int cur = kt & 1;
        if (kt < 31) {                    // 2-phase: issue next-tile loads now
            stage_contig(khead + (size_t)(kt + 1) * 64 * 64, lds + 8192 + (cur ^ 1) * 8192, w, lane);
            stage_vt_tile(vhead, kt + 1, lds + 24576 + (cur ^ 1) * 8192, w, lane);
        }
        const char* kc = lds + 8192 + cur * 8192;
        const char* vc = lds + 24576 + cur * 8192;

        // ---- S^T = K . Q^T (scores in log2 domain via QSCALE)
        f32x4 st[4];
        __builtin_amdgcn_s_setprio(1);
#pragma unroll
        for (int mt = 0; mt < 4; ++mt) {
            int kvrow = 16 * mt + q;
            f32x4 c = (f32x4){0.f, 0.f, 0.f, 0.f};
            c = __builtin_amdgcn_mfma_f32_16x16x32_bf16(frag_read(kc, kvrow, 8 * g), bq0, c, 0, 0, 0);
            c = __builtin_amdgcn_mfma_f32_16x16x32_bf16(frag_read(kc, kvrow, 32 + 8 * g), bq1, c, 0, 0, 0);
            st[mt] = c;
        }
        __builtin_amdgcn_s_setprio(0);

        // ---- online softmax, exp2 domain, defer-max (T13)
        float tmax = fmaxf(fmaxf(st[0][0], st[0][1]), fmaxf(st[0][2], st[0][3]));
#pragma unroll
        for (int mt = 1; mt < 4; ++mt)
            tmax = fmaxf(tmax, fmaxf(fmaxf(st[mt][0], st[mt][1]),
                                     fmaxf(st[mt][2], st[mt][3])));
        tmax = fmaxf(tmax, __shfl_xor(tmax, 16));
        tmax = fmaxf(tmax, __shfl_xor(tmax, 32));
        if (!__all(tmax - mrun <= DEFER_THR)) {
            float mnew = fmaxf(mrun, tmax);
            float corr = exp2_hw(mrun - mnew);
            lsum *= corr;                 // partial-sum rescale (distributive)
#pragma unroll
            for (int i = 0; i < 4; ++i) {
                acc[i][0] *= corr; acc[i][1] *= corr;
                acc[i][2] *= corr; acc[i][3] *= corr;
            }
            mrun = mnew;
        }
        float p[16];
#pragma unroll
        for (int mt = 0; mt < 4; ++mt)
#pragma unroll
            for (int r = 0; r < 4; ++r) {
                float e = exp2_hw(st[mt][r] - mrun);
                p[4 * mt + r] = e;
                lsum += e;                // merged once, in the epilogue
            }

        // ---- P^T -> PV B-fragments: cvt_pk pairs + register shuffle
        unsigned pk0[4], pk1[4];
#pragma unroll
        for (int mt = 0; mt < 4; ++mt) {
            pk0[mt] = cvt_pk_bf16(p[4 * mt + 0], p[4 * mt + 1]);
            pk1[mt] = cvt_pk_bf16(p[4 * mt + 2], p[4 * mt + 3]);
        }
        union { bf16x8 v; unsigned u[4]; } bp0, bp1;
        {
            unsigned xa0 = __shfl(pk0[0], srcA), ya0 = __shfl(pk0[1], srcA);
            unsigned xa1 = __shfl(pk1[0], srcA), ya1 = __shfl(pk1[1], srcA);
            unsigned xb0 = __shfl(pk0[0], srcB), yb0 = __shfl(pk0[1], srcB);
            unsigned xb1 = __shfl(pk1[0], srcB), yb1 = __shfl(pk1[1], srcB);
            bp0.u[0] = hiSel ? ya0 : xa0;
            bp0.u[1] = hiSel ? ya1 : xa1;
            bp0.u[2] = hiSel ? yb0 : xb0;
            bp0.u[3] = hiSel ? yb1 : xb1;
        }
        {
            unsigned xa0 = __shfl(pk0[2], srcA), ya0 = __shfl(pk0[3], srcA);
            unsigned xa1 = __shfl(pk1[2], srcA), ya1 = __shfl(pk1[3], srcA);
            unsigned xb0 = __shfl(pk0[2], srcB), yb0 = __shfl(pk0[3], srcB);
            unsigned xb1 = __shfl(pk1[2], srcB), yb1 = __shfl(pk1[3], srcB);
            bp1.u[0] = hiSel ? ya0 : xa0;
            bp1.u[1] = hiSel ? ya1 : xa1;
            bp1.u[2] = hiSel ? yb0 : xb0;
            bp1.u[3] = hiSel ? yb1 : xb1;
        }

        // ---- O^T += V^T . P^T
        __builtin_amdgcn_s_setprio(1);
#pragma unroll
        for (int nt = 0; nt < 4; ++nt) {
            int nrow = 16 * nt + q;
            acc[nt] = __builtin_amdgcn_mfma_f32_16x16x32_bf16(frag_read(vc, nrow, 8 * g), bp0.v, acc[nt], 0, 0, 0);
            acc[nt] = __builtin_amdgcn_mfma_f32_16x16x32_bf16(frag_read(vc, nrow, 32 + 8 * g), bp1.v, acc[nt], 0, 0, 0);
        }
        __builtin_amdgcn_s_setprio(0);

        __syncthreads();   // drains staging vmcnt + LDS reads; buffers swap
    }

    // ---- merge the 4 group-partials of the row sum (deferred from the loop)
    lsum += __shfl_xor(lsum, 16);
    lsum += __shfl_xor(lsum, 32);

    // ---- epilogue: write ctx as split bf16 planes (hi/lo)
    float inv_l = 1.0f / lsum;
    const int q_abs = qbk * 64 + 16 * w + q;
    size_t obase = ((size_t)b * T_ + q_abs) * 1024 + h * 64;
#pragma unroll
    for (int nt = 0; nt < 4; ++nt)
#pragma unroll
        for (int r = 0; r < 4; ++r) {
            float o = acc[nt][r] * inv_l;
            unsigned short hh = bf16_rne(o);
            union { unsigned u; float f; } hf; hf.u = (unsigned)hh << 16;
            unsigned short ll = bf16_rne(o - hf.f);
            ctx_hi[obase + 16 * nt + 4 * g + r] = hh;
            ctx_lo[obase + 16 * nt + 4 * g + r] = ll;
        }
}

// ---------------------------------------------------------------------------
extern "C" void kernel_launch(void* const* d_in, const int* in_sizes, int n_in,
                              void* d_out, int out_size, void* d_ws, size_t ws_size,
                              hipStream_t stream) {
    const float* x     = (const float*)d_in[0];   // [2,2048,1024]
    const float* w_qkv = (const float*)d_in[1];   // [3072,1024]
    const float* w_out = (const float*)d_in[2];   // [1024,1024]
    const float* b_out = (const float*)d_in[3];   // [1024]
    float* out = (float*)d_out;

    char* base = (char*)d_ws;
    // Phase A (qkv gemm): qkvF @0 (50.3MB); x planes @50.3/58.7MB; wq planes @67.1/73.4MB
    float* qkvF = (float*)base;
    unsigned short* x_hi = (unsigned short*)(base + 50331648);
    unsigned short* x_lo = (unsigned short*)(base + 58720256);
    unsigned short* wq_hi = (unsigned short*)(base + 67108864);
    unsigned short* wq_lo = (unsigned short*)(base + 73400320);
    // Phase B (prep/attn): qb/kb/vt reuse phase-A plane regions (dead after gemm0)
    unsigned short* qb16 = (unsigned short*)(base + 50331648);   // 8MB
    unsigned short* kb16 = (unsigned short*)(base + 58720256);   // 8MB
    unsigned short* vt16 = (unsigned short*)(base + 67108864);   // 8MB
    // Phase C (out gemm): ctx planes + wout planes reuse qkvF region (dead after prep)
    unsigned short* ctx_hi  = (unsigned short*)(base + 0);
    unsigned short* ctx_lo  = (unsigned short*)(base + 8388608);
    unsigned short* wout_hi = (unsigned short*)(base + 16777216);
    unsigned short* wout_lo = (unsigned short*)(base + 18874368);
    // tables
    float* cosT = (float*)(base + 79691776);
    float* sinT = cosT + 65536;

    // splits(x, w_qkv) + rope tables in one launch
    fused_prep<<<3840, 256, 0, stream>>>(x, w_qkv, x_hi, x_lo, wq_hi, wq_lo, cosT, sinT);
    gemm_split<0><<<dim3(24, 32), 256, 0, stream>>>(x_hi, x_lo, wq_hi, wq_lo,
                                                    nullptr, qkvF, 4096, 3072, 1024);
    prep_attn<<<dim3(32, 32), 256, 0, stream>>>(qkvF, cosT, sinT, qb16, kb16, vt16);
    // w_out split must wait until prep_attn has consumed qkvF (aliased region)
    split_kernel<<<512, 256, 0, stream>>>(w_out, wout_hi, wout_lo, 131072);
    attn_mfma<<<dim3(32, 32), 256, 0, stream>>>(qb16, kb16, vt16, ctx_hi, ctx_lo);
    gemm_split_n64<1><<<dim3(16, 32), 256, 0, stream>>>(ctx_hi, ctx_lo, wout_hi, wout_lo,
                                                        b_out, out, 4096, 1024, 1024);
}